// Round 1
// baseline (393.276 us; speedup 1.0000x reference)
//
#include <hip/hip_runtime.h>
#include <cstdint>
#include <cstddef>

// Problem constants
#define DIMN 1024
#define SEQ  2048
#define NBAT 4
#define TOKS (NBAT * SEQ)   // 8192

typedef unsigned short u16;
typedef unsigned int   u32;

typedef __bf16 bf16x8 __attribute__((ext_vector_type(8)));
typedef float  f32x4  __attribute__((ext_vector_type(4)));

#define AS1 __attribute__((address_space(1)))
#define AS3 __attribute__((address_space(3)))

// ---- helpers ----------------------------------------------------------------

__device__ __forceinline__ u16 f2b(float f) {
  union { float f; u32 u; } v; v.f = f;
  u32 r = v.u + 0x7fffu + ((v.u >> 16) & 1u);   // round-to-nearest-even
  return (u16)(r >> 16);
}

__device__ __forceinline__ float b2f(u16 b) {
  union { u32 u; float f; } v; v.u = ((u32)b) << 16;
  return v.f;
}

__device__ __forceinline__ float gelu_exact(float v) {
  return 0.5f * v * (1.0f + erff(v * 0.70710678118654752f));
}

__device__ __forceinline__ void blk_sum2(float& a, float& b, float* sm) {
  #pragma unroll
  for (int o = 32; o >= 1; o >>= 1) {
    a += __shfl_xor(a, o, 64);
    b += __shfl_xor(b, o, 64);
  }
  int w = threadIdx.x >> 6;
  if ((threadIdx.x & 63) == 0) { sm[w] = a; sm[4 + w] = b; }
  __syncthreads();
  a = sm[0] + sm[1] + sm[2] + sm[3];
  b = sm[4] + sm[5] + sm[6] + sm[7];
  __syncthreads();
}

__device__ __forceinline__ float blk_max(float a, float* sm) {
  #pragma unroll
  for (int o = 32; o >= 1; o >>= 1) a = fmaxf(a, __shfl_xor(a, o, 64));
  int w = threadIdx.x >> 6;
  if ((threadIdx.x & 63) == 0) sm[w] = a;
  __syncthreads();
  float r = fmaxf(fmaxf(sm[0], sm[1]), fmaxf(sm[2], sm[3]));
  __syncthreads();
  return r;
}

__device__ __forceinline__ float blk_sum1(float a, float* sm) {
  #pragma unroll
  for (int o = 32; o >= 1; o >>= 1) a += __shfl_xor(a, o, 64);
  int w = threadIdx.x >> 6;
  if ((threadIdx.x & 63) == 0) sm[w] = a;
  __syncthreads();
  float r = sm[0] + sm[1] + sm[2] + sm[3];
  __syncthreads();
  return r;
}

// ---- prep kernels -----------------------------------------------------------

__global__ __launch_bounds__(256) void conv_x(const float* __restrict__ x,
                                              u16* __restrict__ xb) {
  size_t i = ((size_t)blockIdx.x * 256 + threadIdx.x) * 4;
  float4 v = *(const float4*)(x + i);
  uint2 o;
  o.x = (u32)f2b(v.x) | ((u32)f2b(v.y) << 16);
  o.y = (u32)f2b(v.z) | ((u32)f2b(v.w) << 16);
  *(uint2*)(xb + i) = o;
}

// All 5 weight transposes in one dispatch: W [K][N] f32 -> WT [N][K] bf16.
__global__ __launch_bounds__(256) void transpose_w5(
    const float* __restrict__ Wq, const float* __restrict__ Wk,
    const float* __restrict__ Wv, const float* __restrict__ W1,
    const float* __restrict__ W2,
    u16* __restrict__ Wqkv, u16* __restrict__ W1T, u16* __restrict__ W2T)
{
  const float* W; u16* T;
  switch (blockIdx.z) {
    case 0: W = Wq; T = Wqkv;                      break;
    case 1: W = Wk; T = Wqkv + 1 * DIMN * DIMN;    break;
    case 2: W = Wv; T = Wqkv + 2 * DIMN * DIMN;    break;
    case 3: W = W1; T = W1T;                       break;
    default: W = W2; T = W2T;                      break;
  }
  __shared__ float t[32][33];
  int tx = threadIdx.x, ty = threadIdx.y;
  int k0 = blockIdx.x * 32, n0 = blockIdx.y * 32;
  #pragma unroll
  for (int j = 0; j < 32; j += 8)
    t[ty + j][tx] = W[(size_t)(k0 + ty + j) * DIMN + n0 + tx];
  __syncthreads();
  #pragma unroll
  for (int j = 0; j < 32; j += 8)
    T[(size_t)(n0 + ty + j) * DIMN + k0 + tx] = f2b(t[tx][ty + j]);
}

// Vb[b][tok][d] bf16 -> VT[b][d][tok] bf16
__global__ __launch_bounds__(256) void transpose_v(const u16* __restrict__ Vb,
                                                   u16* __restrict__ VT) {
  __shared__ u16 t[32][33];
  int tx = threadIdx.x, ty = threadIdx.y;
  int d0 = blockIdx.x * 32, t0 = blockIdx.y * 32;
  const u16* src = Vb + (size_t)blockIdx.z * SEQ * DIMN;
  u16*       dst = VT + (size_t)blockIdx.z * DIMN * SEQ;
  #pragma unroll
  for (int j = 0; j < 32; j += 8)
    t[ty + j][tx] = src[(size_t)(t0 + ty + j) * DIMN + d0 + tx];
  __syncthreads();
  #pragma unroll
  for (int j = 0; j < 32; j += 8)
    dst[(size_t)(d0 + ty + j) * SEQ + t0 + tx] = t[tx][ty + j];
}

// ---- MFMA GEMM: C[M,N] = A[M,K] * B^T  (128x128 tile, legacy path) ----------
// Kept for PV and FFN shapes (their 256^2 grids would underfill 256 CUs).
template <int EPI, int SWZ>
__global__ __launch_bounds__(256) void gemm_bt(
    const u16* __restrict__ A, const u16* __restrict__ Bm,
    u16* __restrict__ Cb, u16* __restrict__ Cb2, u16* __restrict__ Cb3,
    const float* __restrict__ bias, const float* __restrict__ bias2,
    const float* __restrict__ bias3,
    int M, int N, int K, int ldc,
    size_t sA, size_t sB, size_t sC)
{
  __shared__ u16 As[128 * 64];
  __shared__ u16 Bs[128 * 64];

  const int tid = threadIdx.x;

  int bm0, bn0;
  if (SWZ == 1) {
    const int id   = blockIdx.y * gridDim.x + blockIdx.x;
    const int xcd  = id & 7;
    const int idx  = id >> 3;
    const int band = gridDim.x >> 3;
    const int bm_l = idx % band;
    const int bn   = idx / band;
    bm0 = (xcd * band + bm_l) * 128;
    bn0 = bn * 128;
  } else {
    bm0 = blockIdx.x * 128;
    bn0 = blockIdx.y * 128;
  }

  A  += (size_t)blockIdx.z * sA;
  Bm += (size_t)blockIdx.z * sB;
  const int wave = tid >> 6, lane = tid & 63;
  const int wm   = (wave >> 1) * 64, wn = (wave & 1) * 64;
  const int l16  = lane & 15, quad = lane >> 4;

  f32x4 acc[4][4] = {};

  for (int k0 = 0; k0 < K; k0 += 64) {
    #pragma unroll
    for (int j = 0; j < 4; ++j) {
      const int c  = wave * 256 + j * 64 + lane;
      const int r  = c >> 3;
      const int cg = (c & 7) ^ (r & 7);
      const u16* gA = A  + (size_t)(bm0 + r) * K + k0 + cg * 8;
      const u16* gB = Bm + (size_t)(bn0 + r) * K + k0 + cg * 8;
      u16* lA = As + (wave * 4 + j) * 512;
      u16* lB = Bs + (wave * 4 + j) * 512;
      __builtin_amdgcn_global_load_lds((const AS1 void*)gA, (AS3 void*)lA, 16, 0, 0);
      __builtin_amdgcn_global_load_lds((const AS1 void*)gB, (AS3 void*)lB, 16, 0, 0);
    }
    __syncthreads();

    #pragma unroll
    for (int kk = 0; kk < 64; kk += 32) {
      const int kc = kk >> 3;
      const int sw = l16 & 7;
      bf16x8 af[4], bfr[4];
      #pragma unroll
      for (int t = 0; t < 4; ++t) {
        const int row = wm + t * 16 + l16;
        af[t] = *(const bf16x8*)(&As[row * 64 + (((kc + quad) ^ sw) << 3)]);
      }
      #pragma unroll
      for (int t = 0; t < 4; ++t) {
        const int row = wn + t * 16 + l16;
        bfr[t] = *(const bf16x8*)(&Bs[row * 64 + (((kc + quad) ^ sw) << 3)]);
      }
      #pragma unroll
      for (int mt = 0; mt < 4; ++mt)
        #pragma unroll
        for (int nt = 0; nt < 4; ++nt)
          acc[mt][nt] = __builtin_amdgcn_mfma_f32_16x16x32_bf16(
              af[mt], bfr[nt], acc[mt][nt], 0, 0, 0);
    }
    __syncthreads();
  }

  u16* Cbz = Cb + (size_t)blockIdx.z * sC;

  #pragma unroll
  for (int mt = 0; mt < 4; ++mt) {
    int grow0 = bm0 + wm + mt * 16 + quad * 4;
    #pragma unroll
    for (int nt = 0; nt < 4; ++nt) {
      int gcol = bn0 + wn + nt * 16 + l16;
      if (EPI == 3) {
        const int seg = gcol >> 10;
        const int col = gcol & 1023;
        const float* bp = (seg == 0) ? bias : (seg == 1) ? bias2 : bias3;
        u16*         cp = (seg == 0) ? Cb   : (seg == 1) ? Cb2   : Cb3;
        float bv = bp[col];
        #pragma unroll
        for (int r = 0; r < 4; ++r)
          cp[(size_t)(grow0 + r) * ldc + col] = f2b(acc[mt][nt][r] + bv);
      } else if (EPI == 4) {
        float bv = bias[gcol];
        #pragma unroll
        for (int r = 0; r < 4; ++r)
          Cbz[(size_t)(grow0 + r) * ldc + gcol] =
              f2b(gelu_exact(acc[mt][nt][r] + bv));
      } else {  // 6
        #pragma unroll
        for (int r = 0; r < 4; ++r)
          Cbz[(size_t)(grow0 + r) * ldc + gcol] = f2b(acc[mt][nt][r]);
      }
    }
  }
}

// ---- 256x256 MFMA GEMM, phase-split K-pipeline ------------------------------
// 512 threads = 8 waves (2M x 4N), wave tile 128x64, acc[8][4] (128 VGPR).
// LDS: 2 x (A[256x64] + B[256x64]) bf16 = 128 KiB double buffer, per-row XOR
// chunk swizzle (same scheme as gemm_bt: 0 bank conflicts measured).
// K-tile = 64. Four phases per K-tile, 16 MFMA each:
//   Ph1 (mhalf0,kk0): issue ALL next-tile stages (8x global_load_lds w=16)
//   Ph2 (mhalf1,kk0)  Ph3 (mhalf0,kk32)  Ph4 (mhalf1,kk32)
// Raw s_barrier between phases (NO vmcnt drain - that drain is the m97-class
// ~20% stall). Single asm vmcnt(0) at the tile boundary: the youngest stage
// was issued 3 phases (~600+ cyc of MFMA) earlier, so its latency is covered.
// setprio(1) around each MFMA cluster (T5: needs the phase role-split).
// sched_barrier(0) fences the boundary so next-tile ds_reads can't hoist
// above the vmcnt guarantee.
template <int EPI, int SWZ>
__global__ __launch_bounds__(512, 2) void gemm256(
    const u16* __restrict__ A, const u16* __restrict__ Bm,
    u16* __restrict__ Cb, u16* __restrict__ Cb2, u16* __restrict__ Cb3,
    const float* __restrict__ bias, const float* __restrict__ bias2,
    const float* __restrict__ bias3,
    int M, int N, int K, int ldc,
    size_t sA, size_t sB, size_t sC)
{
  __shared__ u16 As[2][256 * 64];   // 32 KiB each half-tile buffer
  __shared__ u16 Bs[2][256 * 64];

  const int tid = threadIdx.x;

  int bm0, bn0;
  if (SWZ == 1) {
    const int id   = blockIdx.y * gridDim.x + blockIdx.x;
    const int xcd  = id & 7;
    const int idx  = id >> 3;
    const int band = gridDim.x >> 3;          // bm tiles per XCD
    const int bm_l = idx % band;
    const int bn   = idx / band;
    bm0 = (xcd * band + bm_l) * 256;
    bn0 = bn * 256;
  } else {
    bm0 = blockIdx.x * 256;
    bn0 = blockIdx.y * 256;
  }

  A  += (size_t)blockIdx.z * sA;
  Bm += (size_t)blockIdx.z * sB;

  const int wave = tid >> 6, lane = tid & 63;
  const int wm   = (wave >> 2) * 128, wn = (wave & 3) * 64;
  const int l16  = lane & 15, quad = lane >> 4, sw = l16 & 7;

  f32x4 acc[8][4] = {};

  const int nk = K >> 6;

  // stage K-tile kt into buffer b (A and B tiles, 8 issues per thread)
  auto STAGE = [&](int b, int kt) {
    #pragma unroll
    for (int j = 0; j < 4; ++j) {
      const int c  = wave * 256 + j * 64 + lane;   // 16B slot id, 0..2047
      const int r  = c >> 3;                       // row 0..255
      const int cg = (c & 7) ^ (r & 7);            // XOR chunk swizzle
      const u16* gA = A  + (size_t)(bm0 + r) * K + kt * 64 + cg * 8;
      const u16* gB = Bm + (size_t)(bn0 + r) * K + kt * 64 + cg * 8;
      u16* lA = &As[b][(wave * 256 + j * 64) * 8];   // wave-uniform base
      u16* lB = &Bs[b][(wave * 256 + j * 64) * 8];
      __builtin_amdgcn_global_load_lds((const AS1 void*)gA, (AS3 void*)lA, 16, 0, 0);
      __builtin_amdgcn_global_load_lds((const AS1 void*)gB, (AS3 void*)lB, 16, 0, 0);
    }
  };

  // prologue: tile 0 -> buf 0, full drain once
  STAGE(0, 0);
  asm volatile("s_waitcnt vmcnt(0)" ::: "memory");
  __builtin_amdgcn_s_barrier();
  __builtin_amdgcn_sched_barrier(0);

  for (int t = 0; t < nk; ++t) {
    const u16* Asb = As[t & 1];
    const u16* Bsb = Bs[t & 1];

    bf16x8 af[4], bfr[4];

    // ---- phase 1: (mhalf0, kk=0) + issue next-tile stages
    if (t + 1 < nk) STAGE((t + 1) & 1, t + 1);
    #pragma unroll
    for (int i = 0; i < 4; ++i)
      af[i]  = *(const bf16x8*)(Asb + (wm + i * 16 + l16) * 64 + ((quad ^ sw) << 3));
    #pragma unroll
    for (int i = 0; i < 4; ++i)
      bfr[i] = *(const bf16x8*)(Bsb + (wn + i * 16 + l16) * 64 + ((quad ^ sw) << 3));
    __builtin_amdgcn_s_setprio(1);
    #pragma unroll
    for (int mt = 0; mt < 4; ++mt)
      #pragma unroll
      for (int nt = 0; nt < 4; ++nt)
        acc[mt][nt] = __builtin_amdgcn_mfma_f32_16x16x32_bf16(
            af[mt], bfr[nt], acc[mt][nt], 0, 0, 0);
    __builtin_amdgcn_s_setprio(0);
    __builtin_amdgcn_s_barrier();

    // ---- phase 2: (mhalf1, kk=0) -- B frags reused
    #pragma unroll
    for (int i = 0; i < 4; ++i)
      af[i] = *(const bf16x8*)(Asb + (wm + 64 + i * 16 + l16) * 64 + ((quad ^ sw) << 3));
    __builtin_amdgcn_s_setprio(1);
    #pragma unroll
    for (int mt = 0; mt < 4; ++mt)
      #pragma unroll
      for (int nt = 0; nt < 4; ++nt)
        acc[4 + mt][nt] = __builtin_amdgcn_mfma_f32_16x16x32_bf16(
            af[mt], bfr[nt], acc[4 + mt][nt], 0, 0, 0);
    __builtin_amdgcn_s_setprio(0);
    __builtin_amdgcn_s_barrier();

    // ---- phase 3: (mhalf0, kk=32)
    #pragma unroll
    for (int i = 0; i < 4; ++i)
      af[i]  = *(const bf16x8*)(Asb + (wm + i * 16 + l16) * 64 + (((4 + quad) ^ sw) << 3));
    #pragma unroll
    for (int i = 0; i < 4; ++i)
      bfr[i] = *(const bf16x8*)(Bsb + (wn + i * 16 + l16) * 64 + (((4 + quad) ^ sw) << 3));
    __builtin_amdgcn_s_setprio(1);
    #pragma unroll
    for (int mt = 0; mt < 4; ++mt)
      #pragma unroll
      for (int nt = 0; nt < 4; ++nt)
        acc[mt][nt] = __builtin_amdgcn_mfma_f32_16x16x32_bf16(
            af[mt], bfr[nt], acc[mt][nt], 0, 0, 0);
    __builtin_amdgcn_s_setprio(0);
    __builtin_amdgcn_s_barrier();

    // ---- phase 4: (mhalf1, kk=32)
    #pragma unroll
    for (int i = 0; i < 4; ++i)
      af[i] = *(const bf16x8*)(Asb + (wm + 64 + i * 16 + l16) * 64 + (((4 + quad) ^ sw) << 3));
    __builtin_amdgcn_s_setprio(1);
    #pragma unroll
    for (int mt = 0; mt < 4; ++mt)
      #pragma unroll
      for (int nt = 0; nt < 4; ++nt)
        acc[4 + mt][nt] = __builtin_amdgcn_mfma_f32_16x16x32_bf16(
            af[mt], bfr[nt], acc[4 + mt][nt], 0, 0, 0);
    __builtin_amdgcn_s_setprio(0);

    // tile boundary: next tile's buffer must be fully landed (all waves).
    asm volatile("s_waitcnt vmcnt(0)" ::: "memory");
    __builtin_amdgcn_s_barrier();
    __builtin_amdgcn_sched_barrier(0);
  }

  u16* Cbz = Cb + (size_t)blockIdx.z * sC;

  #pragma unroll
  for (int mt = 0; mt < 8; ++mt) {
    int grow0 = bm0 + wm + mt * 16 + quad * 4;
    #pragma unroll
    for (int nt = 0; nt < 4; ++nt) {
      int gcol = bn0 + wn + nt * 16 + l16;
      if (EPI == 3) {
        const int seg = gcol >> 10;
        const int col = gcol & 1023;
        const float* bp = (seg == 0) ? bias : (seg == 1) ? bias2 : bias3;
        u16*         cp = (seg == 0) ? Cb   : (seg == 1) ? Cb2   : Cb3;
        float bv = bp[col];
        #pragma unroll
        for (int r = 0; r < 4; ++r)
          cp[(size_t)(grow0 + r) * ldc + col] = f2b(acc[mt][nt][r] + bv);
      } else if (EPI == 4) {
        float bv = bias[gcol];
        #pragma unroll
        for (int r = 0; r < 4; ++r)
          Cbz[(size_t)(grow0 + r) * ldc + gcol] =
              f2b(gelu_exact(acc[mt][nt][r] + bv));
      } else {  // 6
        #pragma unroll
        for (int r = 0; r < 4; ++r)
          Cbz[(size_t)(grow0 + r) * ldc + gcol] = f2b(acc[mt][nt][r]);
      }
    }
  }
}

// ---- softmax over rows of 2048 ----------------------------------------------
__global__ __launch_bounds__(256) void softmax_rows(const u16* __restrict__ Sc,
                                                    u16* __restrict__ P) {
  __shared__ float sm[8];
  int row = blockIdx.x, t = threadIdx.x;
  const u16* s = Sc + (size_t)row * SEQ;
  uint4 raw = *(const uint4*)(s + t * 8);
  float v[8];
  #pragma unroll
  for (int m = 0; m < 4; ++m) {
    u32 w = ((const u32*)&raw)[m];
    v[2 * m]     = b2f((u16)(w & 0xffff)) * 0.125f;
    v[2 * m + 1] = b2f((u16)(w >> 16)) * 0.125f;
  }
  float mx = -1e30f;
  #pragma unroll
  for (int i = 0; i < 8; ++i) mx = fmaxf(mx, v[i]);
  mx = blk_max(mx, sm);
  float sum = 0.0f;
  #pragma unroll
  for (int i = 0; i < 8; ++i) { v[i] = __expf(v[i] - mx); sum += v[i]; }
  sum = blk_sum1(sum, sm);
  float inv = 1.0f / sum;
  uint4 o;
  #pragma unroll
  for (int m = 0; m < 4; ++m)
    ((u32*)&o)[m] = (u32)f2b(v[2 * m] * inv) | ((u32)f2b(v[2 * m + 1] * inv) << 16);
  *(uint4*)(P + (size_t)row * SEQ + t * 8) = o;
}

// ---- h = LN( LN(attn+x)*g_at+b_at + x )*g_ln+b_ln  -> hres bf16 -------------
__global__ __launch_bounds__(256) void ln1_fused(
    const u16* __restrict__ attn, const u16* __restrict__ xb,
    const float* __restrict__ g_at, const float* __restrict__ b_at,
    const float* __restrict__ g_ln, const float* __restrict__ b_ln,
    u16* __restrict__ hres)
{
  __shared__ float sm[8];
  int row = blockIdx.x, t = threadIdx.x;
  size_t base = (size_t)row * DIMN;
  uint2 ar = *(const uint2*)(attn + base + t * 4);
  uint2 xr4 = *(const uint2*)(xb + base + t * 4);
  float y[4], xr[4];
  float s = 0.0f, s2 = 0.0f;
  #pragma unroll
  for (int i = 0; i < 4; ++i) {
    u32 aw = ((const u32*)&ar)[i >> 1];
    u32 xw = ((const u32*)&xr4)[i >> 1];
    float av = b2f((u16)((i & 1) ? (aw >> 16) : (aw & 0xffff)));
    xr[i]    = b2f((u16)((i & 1) ? (xw >> 16) : (xw & 0xffff)));
    y[i] = av + xr[i];
    s += y[i]; s2 += y[i] * y[i];
  }
  blk_sum2(s, s2, sm);
  float m  = s * (1.0f / DIMN);
  float rs = rsqrtf(s2 * (1.0f / DIMN) - m * m + 1e-5f);
  float z[4];
  s = 0.0f; s2 = 0.0f;
  #pragma unroll
  for (int i = 0; i < 4; ++i) {
    int c = t * 4 + i;
    float at = (y[i] - m) * rs * g_at[c] + b_at[c];
    z[i] = at + xr[i];
    s += z[i]; s2 += z[i] * z[i];
  }
  blk_sum2(s, s2, sm);
  float m2  = s * (1.0f / DIMN);
  float rs2 = rsqrtf(s2 * (1.0f / DIMN) - m2 * m2 + 1e-5f);
  uint2 o;
  #pragma unroll
  for (int i = 0; i < 2; ++i) {
    int c = t * 4 + 2 * i;
    float h0 = (z[2 * i]     - m2) * rs2 * g_ln[c]     + b_ln[c];
    float h1 = (z[2 * i + 1] - m2) * rs2 * g_ln[c + 1] + b_ln[c + 1];
    ((u32*)&o)[i] = (u32)f2b(h0) | ((u32)f2b(h1) << 16);
  }
  *(uint2*)(hres + base + t * 4) = o;
}

// ---- out = LN(u + hres)*g_ln + b_ln  (bf16 in, f32 out) ---------------------
__global__ __launch_bounds__(256) void ln2_final(
    const u16* __restrict__ u, const u16* __restrict__ hres,
    const float* __restrict__ g, const float* __restrict__ bb,
    float* __restrict__ out)
{
  __shared__ float sm[8];
  int row = blockIdx.x, t = threadIdx.x;
  size_t base = (size_t)row * DIMN;
  uint2 ur = *(const uint2*)(u + base + t * 4);
  uint2 hr = *(const uint2*)(hres + base + t * 4);
  float y[4];
  float s = 0.0f, s2 = 0.0f;
  #pragma unroll
  for (int i = 0; i < 4; ++i) {
    u32 uw = ((const u32*)&ur)[i >> 1];
    u32 hw = ((const u32*)&hr)[i >> 1];
    float uv = b2f((u16)((i & 1) ? (uw >> 16) : (uw & 0xffff)));
    float hv = b2f((u16)((i & 1) ? (hw >> 16) : (hw & 0xffff)));
    y[i] = uv + hv;
    s += y[i]; s2 += y[i] * y[i];
  }
  blk_sum2(s, s2, sm);
  float m  = s * (1.0f / DIMN);
  float rs = rsqrtf(s2 * (1.0f / DIMN) - m * m + 1e-5f);
  float4 o;
  o.x = (y[0] - m) * rs * g[t * 4 + 0] + bb[t * 4 + 0];
  o.y = (y[1] - m) * rs * g[t * 4 + 1] + bb[t * 4 + 1];
  o.z = (y[2] - m) * rs * g[t * 4 + 2] + bb[t * 4 + 2];
  o.w = (y[3] - m) * rs * g[t * 4 + 3] + bb[t * 4 + 3];
  *(float4*)(out + base + t * 4) = o;
}

// ---- launch -----------------------------------------------------------------

extern "C" void kernel_launch(void* const* d_in, const int* in_sizes, int n_in,
                              void* d_out, int out_size, void* d_ws, size_t ws_size,
                              hipStream_t stream)
{
  const float* x    = (const float*)d_in[0];
  const float* Wq   = (const float*)d_in[1];
  const float* bq   = (const float*)d_in[2];
  const float* Wk   = (const float*)d_in[3];
  const float* bk   = (const float*)d_in[4];
  const float* Wv   = (const float*)d_in[5];
  const float* bv   = (const float*)d_in[6];
  const float* g_at = (const float*)d_in[7];
  const float* b_at = (const float*)d_in[8];
  const float* g_ln = (const float*)d_in[9];
  const float* b_ln = (const float*)d_in[10];
  const float* W1   = (const float*)d_in[11];
  const float* c1   = (const float*)d_in[12];
  const float* W2   = (const float*)d_in[13];
  const float* c2   = (const float*)d_in[14];
  float* out = (float*)d_out;

  // workspace layout (1 MiB units), peak 154 MiB (unchanged)
  char* ws = (char*)d_ws;
  const size_t MB = 1u << 20;
  u16* xb    = (u16*)(ws + 0 * MB);
  u16* W1T   = (u16*)(ws + 16 * MB);
  u16* W2T   = (u16*)(ws + 18 * MB);
  u16* WqkvT = (u16*)(ws + 20 * MB);
  u16* Qb    = (u16*)(ws + 26 * MB);
  u16* Kb    = (u16*)(ws + 42 * MB);
  u16* Vb    = (u16*)(ws + 58 * MB);
  u16* VT    = (u16*)(ws + 74 * MB);
  u16* Sc    = (u16*)(ws + 90 * MB);
  u16* attn  = (u16*)(ws + 90 * MB);
  u16* hres  = (u16*)(ws + 106 * MB);
  u16* Pb    = (u16*)(ws + 122 * MB);
  u16* tb    = Kb;   // FFN mid, K dead
  u16* ub    = Vb;   // FFN out, Vb dead

  // prep
  conv_x<<<(TOKS * DIMN) / 1024, 256, 0, stream>>>(x, xb);
  transpose_w5<<<dim3(32, 32, 5), dim3(32, 8), 0, stream>>>(
      Wq, Wk, Wv, W1, W2, WqkvT, W1T, W2T);

  // fused QKV projection: [8192,1024] @ [3072,1024]^T on the 256^2 pipeline
  gemm256<3, 1><<<dim3(32, 12), 512, 0, stream>>>(
      xb, WqkvT, Qb, Kb, Vb, bq, bk, bv,
      TOKS, 3 * DIMN, DIMN, DIMN, 0, 0, 0);

  // V -> V^T per batch
  transpose_v<<<dim3(32, 64, NBAT), dim3(32, 8), 0, stream>>>(Vb, VT);

  // scores: 8x8x4 = 256 blocks = exactly 1/CU on the 256^2 pipeline
  gemm256<6, 0><<<dim3(8, 8, NBAT), 512, 0, stream>>>(
      Qb, Kb, Sc, nullptr, nullptr, nullptr, nullptr, nullptr,
      SEQ, SEQ, DIMN, SEQ,
      (size_t)SEQ * DIMN, (size_t)SEQ * DIMN, (size_t)SEQ * SEQ);
  softmax_rows<<<TOKS, 256, 0, stream>>>(Sc, Pb);
  gemm_bt<6, 0><<<dim3(16, 8, NBAT), 256, 0, stream>>>(
      Pb, VT, attn, nullptr, nullptr, nullptr, nullptr, nullptr,
      SEQ, DIMN, SEQ, DIMN,
      (size_t)SEQ * SEQ, (size_t)DIMN * SEQ, (size_t)SEQ * DIMN);

  // h = LN(LN(attn+x)+x) -> hres bf16
  ln1_fused<<<TOKS, 256, 0, stream>>>(attn, xb, g_at, b_at, g_ln, b_ln, hres);

  // FFN (128^2 path: 512 blocks each keeps all CUs fed)
  gemm_bt<4, 1><<<dim3(64, 8), 256, 0, stream>>>(
      hres, W1T, tb, nullptr, nullptr, c1, nullptr, nullptr,
      TOKS, DIMN, DIMN, DIMN, 0, 0, 0);
  gemm_bt<4, 1><<<dim3(64, 8), 256, 0, stream>>>(
      tb, W2T, ub, nullptr, nullptr, c2, nullptr, nullptr,
      TOKS, DIMN, DIMN, DIMN, 0, 0, 0);

  // out = LN(u + h)
  ln2_final<<<TOKS, 256, 0, stream>>>(ub, hres, g_ln, b_ln, out);
}

// Round 2
// 379.724 us; speedup vs baseline: 1.0357x; 1.0357x over previous
//
#include <hip/hip_runtime.h>
#include <cstdint>
#include <cstddef>

// Problem constants
#define DIMN 1024
#define SEQ  2048
#define NBAT 4
#define TOKS (NBAT * SEQ)   // 8192

typedef unsigned short u16;
typedef unsigned int   u32;

typedef __bf16 bf16x8 __attribute__((ext_vector_type(8)));
typedef float  f32x4  __attribute__((ext_vector_type(4)));

#define AS1 __attribute__((address_space(1)))
#define AS3 __attribute__((address_space(3)))

// ---- helpers ----------------------------------------------------------------

__device__ __forceinline__ u16 f2b(float f) {
  union { float f; u32 u; } v; v.f = f;
  u32 r = v.u + 0x7fffu + ((v.u >> 16) & 1u);   // round-to-nearest-even
  return (u16)(r >> 16);
}

__device__ __forceinline__ float b2f(u16 b) {
  union { u32 u; float f; } v; v.u = ((u32)b) << 16;
  return v.f;
}

__device__ __forceinline__ float gelu_exact(float v) {
  return 0.5f * v * (1.0f + erff(v * 0.70710678118654752f));
}

__device__ __forceinline__ void blk_sum2(float& a, float& b, float* sm) {
  #pragma unroll
  for (int o = 32; o >= 1; o >>= 1) {
    a += __shfl_xor(a, o, 64);
    b += __shfl_xor(b, o, 64);
  }
  int w = threadIdx.x >> 6;
  if ((threadIdx.x & 63) == 0) { sm[w] = a; sm[4 + w] = b; }
  __syncthreads();
  a = sm[0] + sm[1] + sm[2] + sm[3];
  b = sm[4] + sm[5] + sm[6] + sm[7];
  __syncthreads();
}

__device__ __forceinline__ float blk_max(float a, float* sm) {
  #pragma unroll
  for (int o = 32; o >= 1; o >>= 1) a = fmaxf(a, __shfl_xor(a, o, 64));
  int w = threadIdx.x >> 6;
  if ((threadIdx.x & 63) == 0) sm[w] = a;
  __syncthreads();
  float r = fmaxf(fmaxf(sm[0], sm[1]), fmaxf(sm[2], sm[3]));
  __syncthreads();
  return r;
}

__device__ __forceinline__ float blk_sum1(float a, float* sm) {
  #pragma unroll
  for (int o = 32; o >= 1; o >>= 1) a += __shfl_xor(a, o, 64);
  int w = threadIdx.x >> 6;
  if ((threadIdx.x & 63) == 0) sm[w] = a;
  __syncthreads();
  float r = sm[0] + sm[1] + sm[2] + sm[3];
  __syncthreads();
  return r;
}

// ---- prep kernels -----------------------------------------------------------

__global__ __launch_bounds__(256) void conv_x(const float* __restrict__ x,
                                              u16* __restrict__ xb) {
  size_t i = ((size_t)blockIdx.x * 256 + threadIdx.x) * 4;
  float4 v = *(const float4*)(x + i);
  uint2 o;
  o.x = (u32)f2b(v.x) | ((u32)f2b(v.y) << 16);
  o.y = (u32)f2b(v.z) | ((u32)f2b(v.w) << 16);
  *(uint2*)(xb + i) = o;
}

// All 5 weight transposes in one dispatch: W [K][N] f32 -> WT [N][K] bf16.
__global__ __launch_bounds__(256) void transpose_w5(
    const float* __restrict__ Wq, const float* __restrict__ Wk,
    const float* __restrict__ Wv, const float* __restrict__ W1,
    const float* __restrict__ W2,
    u16* __restrict__ Wqkv, u16* __restrict__ W1T, u16* __restrict__ W2T)
{
  const float* W; u16* T;
  switch (blockIdx.z) {
    case 0: W = Wq; T = Wqkv;                      break;
    case 1: W = Wk; T = Wqkv + 1 * DIMN * DIMN;    break;
    case 2: W = Wv; T = Wqkv + 2 * DIMN * DIMN;    break;
    case 3: W = W1; T = W1T;                       break;
    default: W = W2; T = W2T;                      break;
  }
  __shared__ float t[32][33];
  int tx = threadIdx.x, ty = threadIdx.y;
  int k0 = blockIdx.x * 32, n0 = blockIdx.y * 32;
  #pragma unroll
  for (int j = 0; j < 32; j += 8)
    t[ty + j][tx] = W[(size_t)(k0 + ty + j) * DIMN + n0 + tx];
  __syncthreads();
  #pragma unroll
  for (int j = 0; j < 32; j += 8)
    T[(size_t)(n0 + ty + j) * DIMN + k0 + tx] = f2b(t[tx][ty + j]);
}

// Vb[b][tok][d] bf16 -> VT[b][d][tok] bf16
__global__ __launch_bounds__(256) void transpose_v(const u16* __restrict__ Vb,
                                                   u16* __restrict__ VT) {
  __shared__ u16 t[32][33];
  int tx = threadIdx.x, ty = threadIdx.y;
  int d0 = blockIdx.x * 32, t0 = blockIdx.y * 32;
  const u16* src = Vb + (size_t)blockIdx.z * SEQ * DIMN;
  u16*       dst = VT + (size_t)blockIdx.z * DIMN * SEQ;
  #pragma unroll
  for (int j = 0; j < 32; j += 8)
    t[ty + j][tx] = src[(size_t)(t0 + ty + j) * DIMN + d0 + tx];
  __syncthreads();
  #pragma unroll
  for (int j = 0; j < 32; j += 8)
    dst[(size_t)(d0 + ty + j) * SEQ + t0 + tx] = t[tx][ty + j];
}

// ---- MFMA GEMM: C[M,N] = A[M,K] * B^T  (128x128 tile, legacy path) ----------
// Kept for PV and FFN shapes (their 256^2 grids would underfill 256 CUs).
template <int EPI, int SWZ>
__global__ __launch_bounds__(256) void gemm_bt(
    const u16* __restrict__ A, const u16* __restrict__ Bm,
    u16* __restrict__ Cb, u16* __restrict__ Cb2, u16* __restrict__ Cb3,
    const float* __restrict__ bias, const float* __restrict__ bias2,
    const float* __restrict__ bias3,
    int M, int N, int K, int ldc,
    size_t sA, size_t sB, size_t sC)
{
  __shared__ u16 As[128 * 64];
  __shared__ u16 Bs[128 * 64];

  const int tid = threadIdx.x;

  int bm0, bn0;
  if (SWZ == 1) {
    const int id   = blockIdx.y * gridDim.x + blockIdx.x;
    const int xcd  = id & 7;
    const int idx  = id >> 3;
    const int band = gridDim.x >> 3;
    const int bm_l = idx % band;
    const int bn   = idx / band;
    bm0 = (xcd * band + bm_l) * 128;
    bn0 = bn * 128;
  } else {
    bm0 = blockIdx.x * 128;
    bn0 = blockIdx.y * 128;
  }

  A  += (size_t)blockIdx.z * sA;
  Bm += (size_t)blockIdx.z * sB;
  const int wave = tid >> 6, lane = tid & 63;
  const int wm   = (wave >> 1) * 64, wn = (wave & 1) * 64;
  const int l16  = lane & 15, quad = lane >> 4;

  f32x4 acc[4][4] = {};

  for (int k0 = 0; k0 < K; k0 += 64) {
    #pragma unroll
    for (int j = 0; j < 4; ++j) {
      const int c  = wave * 256 + j * 64 + lane;
      const int r  = c >> 3;
      const int cg = (c & 7) ^ (r & 7);
      const u16* gA = A  + (size_t)(bm0 + r) * K + k0 + cg * 8;
      const u16* gB = Bm + (size_t)(bn0 + r) * K + k0 + cg * 8;
      u16* lA = As + (wave * 4 + j) * 512;
      u16* lB = Bs + (wave * 4 + j) * 512;
      __builtin_amdgcn_global_load_lds((const AS1 void*)gA, (AS3 void*)lA, 16, 0, 0);
      __builtin_amdgcn_global_load_lds((const AS1 void*)gB, (AS3 void*)lB, 16, 0, 0);
    }
    __syncthreads();

    #pragma unroll
    for (int kk = 0; kk < 64; kk += 32) {
      const int kc = kk >> 3;
      const int sw = l16 & 7;
      bf16x8 af[4], bfr[4];
      #pragma unroll
      for (int t = 0; t < 4; ++t) {
        const int row = wm + t * 16 + l16;
        af[t] = *(const bf16x8*)(&As[row * 64 + (((kc + quad) ^ sw) << 3)]);
      }
      #pragma unroll
      for (int t = 0; t < 4; ++t) {
        const int row = wn + t * 16 + l16;
        bfr[t] = *(const bf16x8*)(&Bs[row * 64 + (((kc + quad) ^ sw) << 3)]);
      }
      #pragma unroll
      for (int mt = 0; mt < 4; ++mt)
        #pragma unroll
        for (int nt = 0; nt < 4; ++nt)
          acc[mt][nt] = __builtin_amdgcn_mfma_f32_16x16x32_bf16(
              af[mt], bfr[nt], acc[mt][nt], 0, 0, 0);
    }
    __syncthreads();
  }

  u16* Cbz = Cb + (size_t)blockIdx.z * sC;

  #pragma unroll
  for (int mt = 0; mt < 4; ++mt) {
    int grow0 = bm0 + wm + mt * 16 + quad * 4;
    #pragma unroll
    for (int nt = 0; nt < 4; ++nt) {
      int gcol = bn0 + wn + nt * 16 + l16;
      if (EPI == 3) {
        const int seg = gcol >> 10;
        const int col = gcol & 1023;
        const float* bp = (seg == 0) ? bias : (seg == 1) ? bias2 : bias3;
        u16*         cp = (seg == 0) ? Cb   : (seg == 1) ? Cb2   : Cb3;
        float bv = bp[col];
        #pragma unroll
        for (int r = 0; r < 4; ++r)
          cp[(size_t)(grow0 + r) * ldc + col] = f2b(acc[mt][nt][r] + bv);
      } else if (EPI == 4) {
        float bv = bias[gcol];
        #pragma unroll
        for (int r = 0; r < 4; ++r)
          Cbz[(size_t)(grow0 + r) * ldc + gcol] =
              f2b(gelu_exact(acc[mt][nt][r] + bv));
      } else {  // 6
        #pragma unroll
        for (int r = 0; r < 4; ++r)
          Cbz[(size_t)(grow0 + r) * ldc + gcol] = f2b(acc[mt][nt][r]);
      }
    }
  }
}

// ---- 256x256 MFMA GEMM, m201-style 8-phase K-pipeline -----------------------
// 512 threads = 8 waves (2M x 4N), wave tile 128x64, acc[8][4].
// LDS AB[buf][A/B][khalf][256 rows x 32 cols] bf16 = 8 x 16 KiB = 128 KiB.
// K-tile = 64 split into two K-halves of 32. Tile t0=2i -> buf0, t1=2i+1 -> buf1.
// 8 phases/iter, phase = (tile, khalf kk, mhalf mh), 16 MFMA each. B-frags
// (4 x bf16x8) loaded on mh0 phases, reused on mh1.
// Staging: 1 unit (256x32 = 2 x global_load_lds w16/thread) per phase:
//   P1: t1.A.k1  P2: t1.B.k1  P3: t2.A.k0  P4: t2.B.k0
//   P5: t2.A.k1  P6: t2.B.k1  P7: t3.A.k0  P8: t3.B.k0
// Each stage lands in a region freed exactly one phase earlier; each unit's
// first read is 6 phases after issue. Counted s_waitcnt vmcnt(8) at the END
// of even phases guarantees the unit needed next phase (4 units = 8 loads in
// flight, never a drain). Tail iteration: waits tighten 8/4/0, stages for
// tiles >= nk skipped.
// Swizzle: phys_chunk = logical_chunk ^ ((row>>1)&3) both on the staging
// global source and the ds_read address (both-sides involution); b128 reads
// land 2 lanes/bank-group per 16-lane service group = conflict-free.
template <int EPI, int SWZ>
__global__ __launch_bounds__(512, 2) void gemm256(
    const u16* __restrict__ A, const u16* __restrict__ Bm,
    u16* __restrict__ Cb, u16* __restrict__ Cb2, u16* __restrict__ Cb3,
    const float* __restrict__ bias, const float* __restrict__ bias2,
    const float* __restrict__ bias3,
    int M, int N, int K, int ldc,
    size_t sA, size_t sB, size_t sC)
{
  __shared__ u16 AB[2][2][2][256 * 32];   // [buf][A/B][khalf][row*32+col]

  const int tid = threadIdx.x;

  int bm0, bn0;
  if (SWZ == 1) {
    const int id   = blockIdx.y * gridDim.x + blockIdx.x;
    const int xcd  = id & 7;
    const int idx  = id >> 3;
    const int band = gridDim.x >> 3;          // bm tiles per XCD
    const int bm_l = idx % band;
    const int bn   = idx / band;
    bm0 = (xcd * band + bm_l) * 256;
    bn0 = bn * 256;
  } else {
    bm0 = blockIdx.x * 256;
    bn0 = blockIdx.y * 256;
  }

  A  += (size_t)blockIdx.z * sA;
  Bm += (size_t)blockIdx.z * sB;

  const int wave = tid >> 6, lane = tid & 63;
  const int wm   = (wave >> 2) * 128, wn = (wave & 3) * 64;
  const int l16  = lane & 15, quad = lane >> 4;
  // read-side swizzled chunk offset (u16 units), lane-constant
  const int rs8  = (quad ^ ((l16 >> 1) & 3)) << 3;
  // stage-side swizzled chunk offset (u16 units), lane-constant
  const int cg8  = ((lane & 3) ^ ((lane >> 3) & 3)) << 3;
  const int srow = wave * 32 + (lane >> 2);   // + j*16

  f32x4 acc[8][4] = {};
  bf16x8 af[4], bf[4];

  const int nk  = K >> 6;
  const int nit = nk >> 1;

#define VM8() asm volatile("s_waitcnt vmcnt(8)" ::: "memory")
#define VM4() asm volatile("s_waitcnt vmcnt(4)" ::: "memory")
#define VM0() asm volatile("s_waitcnt vmcnt(0)" ::: "memory")
#define SBAR() __builtin_amdgcn_s_barrier()
#define SCHEDB() __builtin_amdgcn_sched_barrier(0)

  // stage one 256x32 unit: ABI=0 -> A panel, 1 -> B panel
#define STG(BUF, ABI, KH, KT) do {                                             \
    const u16* _P   = (ABI) ? Bm : A;                                          \
    const int _b0   = (ABI) ? bn0 : bm0;                                       \
    const int _kc   = (KT) * 64 + (KH) * 32;                                   \
    _Pragma("unroll")                                                          \
    for (int _j = 0; _j < 2; ++_j) {                                           \
      const u16* _g = _P + (size_t)(_b0 + srow + _j * 16) * K + _kc + cg8;     \
      u16* _l = &AB[BUF][ABI][KH][(wave * 128 + _j * 64) * 8];                 \
      __builtin_amdgcn_global_load_lds((const AS1 void*)_g, (AS3 void*)_l,     \
                                       16, 0, 0);                              \
    }                                                                          \
  } while (0)

#define LDA(BUF, KH, MH) do {                                                  \
    const u16* _u = &AB[BUF][0][KH][0];                                        \
    _Pragma("unroll")                                                          \
    for (int _i = 0; _i < 4; ++_i)                                             \
      af[_i] = *(const bf16x8*)(_u + (wm + (MH) * 64 + _i * 16 + l16) * 32     \
                                  + rs8);                                      \
  } while (0)

#define LDB(BUF, KH) do {                                                      \
    const u16* _u = &AB[BUF][1][KH][0];                                        \
    _Pragma("unroll")                                                          \
    for (int _i = 0; _i < 4; ++_i)                                             \
      bf[_i] = *(const bf16x8*)(_u + (wn + _i * 16 + l16) * 32 + rs8);         \
  } while (0)

#define MMCL(MH) do {                                                          \
    __builtin_amdgcn_s_setprio(1);                                             \
    _Pragma("unroll")                                                          \
    for (int _mt = 0; _mt < 4; ++_mt) {                                        \
      _Pragma("unroll")                                                        \
      for (int _nt = 0; _nt < 4; ++_nt)                                        \
        acc[(MH) * 4 + _mt][_nt] = __builtin_amdgcn_mfma_f32_16x16x32_bf16(    \
            af[_mt], bf[_nt], acc[(MH) * 4 + _mt][_nt], 0, 0, 0);              \
    }                                                                          \
    __builtin_amdgcn_s_setprio(0);                                             \
  } while (0)

  // ---- prologue: t0 full (4 units) + t1.k0 (2 units); wait oldest 2 units
  STG(0, 0, 0, 0); STG(0, 1, 0, 0);      // t0.A.k0, t0.B.k0
  STG(0, 0, 1, 0); STG(0, 1, 1, 0);      // t0.A.k1, t0.B.k1
  STG(1, 0, 0, 1); STG(1, 1, 0, 1);      // t1.A.k0, t1.B.k0
  VM8(); SBAR(); SCHEDB();

  for (int i = 0; i < nit; ++i) {
    const int t1 = 2 * i + 1;
    const bool last = (i == nit - 1);

    // P1: buf0 kk0 mh0 | stage t1.A.k1
    LDA(0, 0, 0); LDB(0, 0);
    STG(1, 0, 1, t1);
    SBAR();
    MMCL(0);
    SBAR(); SCHEDB();

    // P2: buf0 kk0 mh1 | stage t1.B.k1 | wait: t0.k1 ready for P3
    LDA(0, 0, 1);
    STG(1, 1, 1, t1);
    SBAR();
    MMCL(1);
    VM8(); SBAR(); SCHEDB();

    // P3: buf0 kk1 mh0 | stage t2.A.k0
    LDA(0, 1, 0); LDB(0, 1);
    if (!last) STG(0, 0, 0, t1 + 1);
    SBAR();
    MMCL(0);
    SBAR(); SCHEDB();

    // P4: buf0 kk1 mh1 | stage t2.B.k0 | wait: t1.k0 ready for P5
    LDA(0, 1, 1);
    if (!last) STG(0, 1, 0, t1 + 1);
    SBAR();
    MMCL(1);
    if (last) VM4(); else VM8();
    SBAR(); SCHEDB();

    // P5: buf1 kk0 mh0 | stage t2.A.k1
    LDA(1, 0, 0); LDB(1, 0);
    if (!last) STG(0, 0, 1, t1 + 1);
    SBAR();
    MMCL(0);
    SBAR(); SCHEDB();

    // P6: buf1 kk0 mh1 | stage t2.B.k1 | wait: t1.k1 ready for P7
    LDA(1, 0, 1);
    if (!last) STG(0, 1, 1, t1 + 1);
    SBAR();
    MMCL(1);
    if (last) VM0(); else VM8();
    SBAR(); SCHEDB();

    // P7: buf1 kk1 mh0 | stage t3.A.k0
    LDA(1, 1, 0); LDB(1, 1);
    if (!last) STG(1, 0, 0, t1 + 2);
    SBAR();
    MMCL(0);
    SBAR(); SCHEDB();

    // P8: buf1 kk1 mh1 | stage t3.B.k0 | wait: t2.k0 ready for next P1
    LDA(1, 1, 1);
    if (!last) STG(1, 1, 0, t1 + 2);
    SBAR();
    MMCL(1);
    if (!last) { VM8(); }
    SBAR(); SCHEDB();
  }

#undef VM8
#undef VM4
#undef VM0
#undef SBAR
#undef SCHEDB
#undef STG
#undef LDA
#undef LDB
#undef MMCL

  u16* Cbz = Cb + (size_t)blockIdx.z * sC;

  // epilogue: C/D layout col = lane&15, row = quad*4 + reg
  #pragma unroll
  for (int mt = 0; mt < 8; ++mt) {
    int grow0 = bm0 + wm + mt * 16 + quad * 4;
    #pragma unroll
    for (int nt = 0; nt < 4; ++nt) {
      int gcol = bn0 + wn + nt * 16 + l16;
      if (EPI == 3) {
        const int seg = gcol >> 10;
        const int col = gcol & 1023;
        const float* bp = (seg == 0) ? bias : (seg == 1) ? bias2 : bias3;
        u16*         cp = (seg == 0) ? Cb   : (seg == 1) ? Cb2   : Cb3;
        float bv = bp[col];
        #pragma unroll
        for (int r = 0; r < 4; ++r)
          cp[(size_t)(grow0 + r) * ldc + col] = f2b(acc[mt][nt][r] + bv);
      } else if (EPI == 4) {
        float bv = bias[gcol];
        #pragma unroll
        for (int r = 0; r < 4; ++r)
          Cbz[(size_t)(grow0 + r) * ldc + gcol] =
              f2b(gelu_exact(acc[mt][nt][r] + bv));
      } else {  // 6
        #pragma unroll
        for (int r = 0; r < 4; ++r)
          Cbz[(size_t)(grow0 + r) * ldc + gcol] = f2b(acc[mt][nt][r]);
      }
    }
  }
}

// ---- softmax over rows of 2048 ----------------------------------------------
__global__ __launch_bounds__(256) void softmax_rows(const u16* __restrict__ Sc,
                                                    u16* __restrict__ P) {
  __shared__ float sm[8];
  int row = blockIdx.x, t = threadIdx.x;
  const u16* s = Sc + (size_t)row * SEQ;
  uint4 raw = *(const uint4*)(s + t * 8);
  float v[8];
  #pragma unroll
  for (int m = 0; m < 4; ++m) {
    u32 w = ((const u32*)&raw)[m];
    v[2 * m]     = b2f((u16)(w & 0xffff)) * 0.125f;
    v[2 * m + 1] = b2f((u16)(w >> 16)) * 0.125f;
  }
  float mx = -1e30f;
  #pragma unroll
  for (int i = 0; i < 8; ++i) mx = fmaxf(mx, v[i]);
  mx = blk_max(mx, sm);
  float sum = 0.0f;
  #pragma unroll
  for (int i = 0; i < 8; ++i) { v[i] = __expf(v[i] - mx); sum += v[i]; }
  sum = blk_sum1(sum, sm);
  float inv = 1.0f / sum;
  uint4 o;
  #pragma unroll
  for (int m = 0; m < 4; ++m)
    ((u32*)&o)[m] = (u32)f2b(v[2 * m] * inv) | ((u32)f2b(v[2 * m + 1] * inv) << 16);
  *(uint4*)(P + (size_t)row * SEQ + t * 8) = o;
}

// ---- h = LN( LN(attn+x)*g_at+b_at + x )*g_ln+b_ln  -> hres bf16 -------------
__global__ __launch_bounds__(256) void ln1_fused(
    const u16* __restrict__ attn, const u16* __restrict__ xb,
    const float* __restrict__ g_at, const float* __restrict__ b_at,
    const float* __restrict__ g_ln, const float* __restrict__ b_ln,
    u16* __restrict__ hres)
{
  __shared__ float sm[8];
  int row = blockIdx.x, t = threadIdx.x;
  size_t base = (size_t)row * DIMN;
  uint2 ar = *(const uint2*)(attn + base + t * 4);
  uint2 xr4 = *(const uint2*)(xb + base + t * 4);
  float y[4], xr[4];
  float s = 0.0f, s2 = 0.0f;
  #pragma unroll
  for (int i = 0; i < 4; ++i) {
    u32 aw = ((const u32*)&ar)[i >> 1];
    u32 xw = ((const u32*)&xr4)[i >> 1];
    float av = b2f((u16)((i & 1) ? (aw >> 16) : (aw & 0xffff)));
    xr[i]    = b2f((u16)((i & 1) ? (xw >> 16) : (xw & 0xffff)));
    y[i] = av + xr[i];
    s += y[i]; s2 += y[i] * y[i];
  }
  blk_sum2(s, s2, sm);
  float m  = s * (1.0f / DIMN);
  float rs = rsqrtf(s2 * (1.0f / DIMN) - m * m + 1e-5f);
  float z[4];
  s = 0.0f; s2 = 0.0f;
  #pragma unroll
  for (int i = 0; i < 4; ++i) {
    int c = t * 4 + i;
    float at = (y[i] - m) * rs * g_at[c] + b_at[c];
    z[i] = at + xr[i];
    s += z[i]; s2 += z[i] * z[i];
  }
  blk_sum2(s, s2, sm);
  float m2  = s * (1.0f / DIMN);
  float rs2 = rsqrtf(s2 * (1.0f / DIMN) - m2 * m2 + 1e-5f);
  uint2 o;
  #pragma unroll
  for (int i = 0; i < 2; ++i) {
    int c = t * 4 + 2 * i;
    float h0 = (z[2 * i]     - m2) * rs2 * g_ln[c]     + b_ln[c];
    float h1 = (z[2 * i + 1] - m2) * rs2 * g_ln[c + 1] + b_ln[c + 1];
    ((u32*)&o)[i] = (u32)f2b(h0) | ((u32)f2b(h1) << 16);
  }
  *(uint2*)(hres + base + t * 4) = o;
}

// ---- out = LN(u + hres)*g_ln + b_ln  (bf16 in, f32 out) ---------------------
__global__ __launch_bounds__(256) void ln2_final(
    const u16* __restrict__ u, const u16* __restrict__ hres,
    const float* __restrict__ g, const float* __restrict__ bb,
    float* __restrict__ out)
{
  __shared__ float sm[8];
  int row = blockIdx.x, t = threadIdx.x;
  size_t base = (size_t)row * DIMN;
  uint2 ur = *(const uint2*)(u + base + t * 4);
  uint2 hr = *(const uint2*)(hres + base + t * 4);
  float y[4];
  float s = 0.0f, s2 = 0.0f;
  #pragma unroll
  for (int i = 0; i < 4; ++i) {
    u32 uw = ((const u32*)&ur)[i >> 1];
    u32 hw = ((const u32*)&hr)[i >> 1];
    float uv = b2f((u16)((i & 1) ? (uw >> 16) : (uw & 0xffff)));
    float hv = b2f((u16)((i & 1) ? (hw >> 16) : (hw & 0xffff)));
    y[i] = uv + hv;
    s += y[i]; s2 += y[i] * y[i];
  }
  blk_sum2(s, s2, sm);
  float m  = s * (1.0f / DIMN);
  float rs = rsqrtf(s2 * (1.0f / DIMN) - m * m + 1e-5f);
  float4 o;
  o.x = (y[0] - m) * rs * g[t * 4 + 0] + bb[t * 4 + 0];
  o.y = (y[1] - m) * rs * g[t * 4 + 1] + bb[t * 4 + 1];
  o.z = (y[2] - m) * rs * g[t * 4 + 2] + bb[t * 4 + 2];
  o.w = (y[3] - m) * rs * g[t * 4 + 3] + bb[t * 4 + 3];
  *(float4*)(out + base + t * 4) = o;
}

// ---- launch -----------------------------------------------------------------

extern "C" void kernel_launch(void* const* d_in, const int* in_sizes, int n_in,
                              void* d_out, int out_size, void* d_ws, size_t ws_size,
                              hipStream_t stream)
{
  const float* x    = (const float*)d_in[0];
  const float* Wq   = (const float*)d_in[1];
  const float* bq   = (const float*)d_in[2];
  const float* Wk   = (const float*)d_in[3];
  const float* bk   = (const float*)d_in[4];
  const float* Wv   = (const float*)d_in[5];
  const float* bv   = (const float*)d_in[6];
  const float* g_at = (const float*)d_in[7];
  const float* b_at = (const float*)d_in[8];
  const float* g_ln = (const float*)d_in[9];
  const float* b_ln = (const float*)d_in[10];
  const float* W1   = (const float*)d_in[11];
  const float* c1   = (const float*)d_in[12];
  const float* W2   = (const float*)d_in[13];
  const float* c2   = (const float*)d_in[14];
  float* out = (float*)d_out;

  // workspace layout (1 MiB units), peak 154 MiB (unchanged)
  char* ws = (char*)d_ws;
  const size_t MB = 1u << 20;
  u16* xb    = (u16*)(ws + 0 * MB);
  u16* W1T   = (u16*)(ws + 16 * MB);
  u16* W2T   = (u16*)(ws + 18 * MB);
  u16* WqkvT = (u16*)(ws + 20 * MB);
  u16* Qb    = (u16*)(ws + 26 * MB);
  u16* Kb    = (u16*)(ws + 42 * MB);
  u16* Vb    = (u16*)(ws + 58 * MB);
  u16* VT    = (u16*)(ws + 74 * MB);
  u16* Sc    = (u16*)(ws + 90 * MB);
  u16* attn  = (u16*)(ws + 90 * MB);
  u16* hres  = (u16*)(ws + 106 * MB);
  u16* Pb    = (u16*)(ws + 122 * MB);
  u16* tb    = Kb;   // FFN mid, K dead
  u16* ub    = Vb;   // FFN out, Vb dead

  // prep
  conv_x<<<(TOKS * DIMN) / 1024, 256, 0, stream>>>(x, xb);
  transpose_w5<<<dim3(32, 32, 5), dim3(32, 8), 0, stream>>>(
      Wq, Wk, Wv, W1, W2, WqkvT, W1T, W2T);

  // fused QKV projection: [8192,1024] @ [3072,1024]^T on the 8-phase pipeline
  gemm256<3, 1><<<dim3(32, 12), 512, 0, stream>>>(
      xb, WqkvT, Qb, Kb, Vb, bq, bk, bv,
      TOKS, 3 * DIMN, DIMN, DIMN, 0, 0, 0);

  // V -> V^T per batch
  transpose_v<<<dim3(32, 64, NBAT), dim3(32, 8), 0, stream>>>(Vb, VT);

  // scores: 8x8x4 = 256 blocks = exactly 1/CU on the 8-phase pipeline
  gemm256<6, 0><<<dim3(8, 8, NBAT), 512, 0, stream>>>(
      Qb, Kb, Sc, nullptr, nullptr, nullptr, nullptr, nullptr,
      SEQ, SEQ, DIMN, SEQ,
      (size_t)SEQ * DIMN, (size_t)SEQ * DIMN, (size_t)SEQ * SEQ);
  softmax_rows<<<TOKS, 256, 0, stream>>>(Sc, Pb);
  gemm_bt<6, 0><<<dim3(16, 8, NBAT), 256, 0, stream>>>(
      Pb, VT, attn, nullptr, nullptr, nullptr, nullptr, nullptr,
      SEQ, DIMN, SEQ, DIMN,
      (size_t)SEQ * SEQ, (size_t)DIMN * SEQ, (size_t)SEQ * DIMN);

  // h = LN(LN(attn+x)+x) -> hres bf16
  ln1_fused<<<TOKS, 256, 0, stream>>>(attn, xb, g_at, b_at, g_ln, b_ln, hres);

  // FFN (128^2 path: 512 blocks each keeps all CUs fed)
  gemm_bt<4, 1><<<dim3(64, 8), 256, 0, stream>>>(
      hres, W1T, tb, nullptr, nullptr, c1, nullptr, nullptr,
      TOKS, DIMN, DIMN, DIMN, 0, 0, 0);
  gemm_bt<4, 1><<<dim3(64, 8), 256, 0, stream>>>(
      tb, W2T, ub, nullptr, nullptr, c2, nullptr, nullptr,
      TOKS, DIMN, DIMN, DIMN, 0, 0, 0);

  // out = LN(u + h)
  ln2_final<<<TOKS, 256, 0, stream>>>(ub, hres, g_ln, b_ln, out);
}

// Round 3
// 370.580 us; speedup vs baseline: 1.0612x; 1.0247x over previous
//
#include <hip/hip_runtime.h>
#include <cstdint>
#include <cstddef>

// Problem constants
#define DIMN 1024
#define SEQ  2048
#define NBAT 4
#define TOKS (NBAT * SEQ)   // 8192

typedef unsigned short u16;
typedef unsigned int   u32;

typedef __bf16 bf16x8 __attribute__((ext_vector_type(8)));
typedef float  f32x4  __attribute__((ext_vector_type(4)));

#define AS1 __attribute__((address_space(1)))
#define AS3 __attribute__((address_space(3)))

// ---- helpers ----------------------------------------------------------------

__device__ __forceinline__ u16 f2b(float f) {
  union { float f; u32 u; } v; v.f = f;
  u32 r = v.u + 0x7fffu + ((v.u >> 16) & 1u);   // round-to-nearest-even
  return (u16)(r >> 16);
}

__device__ __forceinline__ float b2f(u16 b) {
  union { u32 u; float f; } v; v.u = ((u32)b) << 16;
  return v.f;
}

__device__ __forceinline__ float gelu_exact(float v) {
  return 0.5f * v * (1.0f + erff(v * 0.70710678118654752f));
}

__device__ __forceinline__ void blk_sum2(float& a, float& b, float* sm) {
  #pragma unroll
  for (int o = 32; o >= 1; o >>= 1) {
    a += __shfl_xor(a, o, 64);
    b += __shfl_xor(b, o, 64);
  }
  int w = threadIdx.x >> 6;
  if ((threadIdx.x & 63) == 0) { sm[w] = a; sm[4 + w] = b; }
  __syncthreads();
  a = sm[0] + sm[1] + sm[2] + sm[3];
  b = sm[4] + sm[5] + sm[6] + sm[7];
  __syncthreads();
}

__device__ __forceinline__ float blk_max(float a, float* sm) {
  #pragma unroll
  for (int o = 32; o >= 1; o >>= 1) a = fmaxf(a, __shfl_xor(a, o, 64));
  int w = threadIdx.x >> 6;
  if ((threadIdx.x & 63) == 0) sm[w] = a;
  __syncthreads();
  float r = fmaxf(fmaxf(sm[0], sm[1]), fmaxf(sm[2], sm[3]));
  __syncthreads();
  return r;
}

__device__ __forceinline__ float blk_sum1(float a, float* sm) {
  #pragma unroll
  for (int o = 32; o >= 1; o >>= 1) a += __shfl_xor(a, o, 64);
  int w = threadIdx.x >> 6;
  if ((threadIdx.x & 63) == 0) sm[w] = a;
  __syncthreads();
  float r = sm[0] + sm[1] + sm[2] + sm[3];
  __syncthreads();
  return r;
}

// ---- prep kernels -----------------------------------------------------------

__global__ __launch_bounds__(256) void conv_x(const float* __restrict__ x,
                                              u16* __restrict__ xb) {
  size_t i = ((size_t)blockIdx.x * 256 + threadIdx.x) * 4;
  float4 v = *(const float4*)(x + i);
  uint2 o;
  o.x = (u32)f2b(v.x) | ((u32)f2b(v.y) << 16);
  o.y = (u32)f2b(v.z) | ((u32)f2b(v.w) << 16);
  *(uint2*)(xb + i) = o;
}

// All 5 weight transposes in one dispatch: W [K][N] f32 -> WT [N][K] bf16.
__global__ __launch_bounds__(256) void transpose_w5(
    const float* __restrict__ Wq, const float* __restrict__ Wk,
    const float* __restrict__ Wv, const float* __restrict__ W1,
    const float* __restrict__ W2,
    u16* __restrict__ Wqkv, u16* __restrict__ W1T, u16* __restrict__ W2T)
{
  const float* W; u16* T;
  switch (blockIdx.z) {
    case 0: W = Wq; T = Wqkv;                      break;
    case 1: W = Wk; T = Wqkv + 1 * DIMN * DIMN;    break;
    case 2: W = Wv; T = Wqkv + 2 * DIMN * DIMN;    break;
    case 3: W = W1; T = W1T;                       break;
    default: W = W2; T = W2T;                      break;
  }
  __shared__ float t[32][33];
  int tx = threadIdx.x, ty = threadIdx.y;
  int k0 = blockIdx.x * 32, n0 = blockIdx.y * 32;
  #pragma unroll
  for (int j = 0; j < 32; j += 8)
    t[ty + j][tx] = W[(size_t)(k0 + ty + j) * DIMN + n0 + tx];
  __syncthreads();
  #pragma unroll
  for (int j = 0; j < 32; j += 8)
    T[(size_t)(n0 + ty + j) * DIMN + k0 + tx] = f2b(t[tx][ty + j]);
}

// Vb[b][tok][d] bf16 -> VT[b][d][tok] bf16
__global__ __launch_bounds__(256) void transpose_v(const u16* __restrict__ Vb,
                                                   u16* __restrict__ VT) {
  __shared__ u16 t[32][33];
  int tx = threadIdx.x, ty = threadIdx.y;
  int d0 = blockIdx.x * 32, t0 = blockIdx.y * 32;
  const u16* src = Vb + (size_t)blockIdx.z * SEQ * DIMN;
  u16*       dst = VT + (size_t)blockIdx.z * DIMN * SEQ;
  #pragma unroll
  for (int j = 0; j < 32; j += 8)
    t[ty + j][tx] = src[(size_t)(t0 + ty + j) * DIMN + d0 + tx];
  __syncthreads();
  #pragma unroll
  for (int j = 0; j < 32; j += 8)
    dst[(size_t)(d0 + ty + j) * SEQ + t0 + tx] = t[tx][ty + j];
}

// ---- 128x128 MFMA GEMM, counted-vmcnt K-pipeline, 2 blocks/CU ---------------
// C[M,N] = A[M,K] * B^T (B given [N][K]). 256 threads = 4 waves (2M x 2N),
// wave tile 64x64, acc[4][4]. BK=64, double-buffered.
// LDS AB[buf][A/B][khalf][128x32] bf16 = 8 x 8 KiB = 64 KiB -> 2 blocks/CU
// (16 waves/CU): cross-block TLP fills barrier/wait gaps (the m97 implicit-
// overlap mechanism) on top of the in-block pipeline.
// 2 phases per K-tile (kk=0,32), 16 MFMA each. Staging for tile t+1 happens
// during tile t (buffer t+1 is fully free then): phase kk stages the
// (t+1, khalf=kk) group = A-unit + B-unit = 4 global_load_lds w16 per thread.
// Counted s_waitcnt vmcnt(4) at EVERY phase end (8 in flight, wait oldest 4;
// never a drain in steady state; issue-to-deadline = 2 phases). Tail: P1 of
// the last tile waits vmcnt(0) (only 4 outstanding, issued 2 phases earlier).
// One s_barrier per phase: reads of buf are protected by the previous phase's
// VM+SBAR; staging targets the OTHER buffer so there is no intra-tile WAR.
// Swizzle (both-sides involution, 0 conflicts measured on this scheme):
//   phys_chunk = logical_chunk ^ ((row>>1)&3) within each 32-col khalf.
// EPI: 3 = QKV routed (+bias per 1024-segment, bf16 to Cb/Cb2/Cb3)
//      4 = +bias, GELU, bf16
//      6 = plain bf16
template <int EPI, int SWZ>
__global__ __launch_bounds__(256, 2) void gemm128p(
    const u16* __restrict__ A, const u16* __restrict__ Bm,
    u16* __restrict__ Cb, u16* __restrict__ Cb2, u16* __restrict__ Cb3,
    const float* __restrict__ bias, const float* __restrict__ bias2,
    const float* __restrict__ bias3,
    int M, int N, int K, int ldc,
    size_t sA, size_t sB, size_t sC)
{
  __shared__ u16 AB[2][2][2][128 * 32];   // [buf][A/B][khalf][row*32+col]

  const int tid = threadIdx.x;

  int bm0, bn0;
  if (SWZ == 1) {
    const int id   = blockIdx.y * gridDim.x + blockIdx.x;
    const int xcd  = id & 7;
    const int idx  = id >> 3;
    const int band = gridDim.x >> 3;          // bm tiles per XCD
    const int bm_l = idx % band;
    const int bn   = idx / band;
    bm0 = (xcd * band + bm_l) * 128;
    bn0 = bn * 128;
  } else {
    bm0 = blockIdx.x * 128;
    bn0 = blockIdx.y * 128;
  }

  A  += (size_t)blockIdx.z * sA;
  Bm += (size_t)blockIdx.z * sB;

  const int wave = tid >> 6, lane = tid & 63;
  const int wm   = (wave >> 1) * 64, wn = (wave & 1) * 64;
  const int l16  = lane & 15, quad = lane >> 4;
  // read-side swizzled chunk offset (u16 units), lane-constant
  const int rs8  = (quad ^ ((l16 >> 1) & 3)) << 3;
  // stage-side swizzled chunk offset (u16 units), lane-constant
  const int cg8  = ((lane & 3) ^ ((lane >> 3) & 3)) << 3;
  const int srow = wave * 32 + (lane >> 2);   // + j*16 covers rows 0..127

  f32x4 acc[4][4] = {};
  bf16x8 af[4], bf[4];

  const int nk = K >> 6;

#define VM4() asm volatile("s_waitcnt vmcnt(4)" ::: "memory")
#define VM0() asm volatile("s_waitcnt vmcnt(0)" ::: "memory")
#define SBAR() __builtin_amdgcn_s_barrier()
#define SCHEDB() __builtin_amdgcn_sched_barrier(0)

  // stage one khalf group (A-unit 128x32 + B-unit 128x32) of tile KT into BUF:
  // 4 global_load_lds per thread
#define STG(BUF, KH, KT) do {                                                  \
    const int _kc = (KT) * 64 + (KH) * 32;                                     \
    _Pragma("unroll")                                                          \
    for (int _j = 0; _j < 2; ++_j) {                                           \
      const u16* _gA = A  + (size_t)(bm0 + srow + _j * 16) * K + _kc + cg8;    \
      const u16* _gB = Bm + (size_t)(bn0 + srow + _j * 16) * K + _kc + cg8;    \
      u16* _lA = &AB[BUF][0][KH][(wave * 128 + _j * 64) * 8];                  \
      u16* _lB = &AB[BUF][1][KH][(wave * 128 + _j * 64) * 8];                  \
      __builtin_amdgcn_global_load_lds((const AS1 void*)_gA, (AS3 void*)_lA,   \
                                       16, 0, 0);                              \
      __builtin_amdgcn_global_load_lds((const AS1 void*)_gB, (AS3 void*)_lB,   \
                                       16, 0, 0);                              \
    }                                                                          \
  } while (0)

#define LDA(BUF, KH) do {                                                      \
    const u16* _u = &AB[BUF][0][KH][0];                                        \
    _Pragma("unroll")                                                          \
    for (int _i = 0; _i < 4; ++_i)                                             \
      af[_i] = *(const bf16x8*)(_u + (wm + _i * 16 + l16) * 32 + rs8);         \
  } while (0)

#define LDB(BUF, KH) do {                                                      \
    const u16* _u = &AB[BUF][1][KH][0];                                        \
    _Pragma("unroll")                                                          \
    for (int _i = 0; _i < 4; ++_i)                                             \
      bf[_i] = *(const bf16x8*)(_u + (wn + _i * 16 + l16) * 32 + rs8);         \
  } while (0)

#define MMCL() do {                                                            \
    __builtin_amdgcn_s_setprio(1);                                             \
    _Pragma("unroll")                                                          \
    for (int _mt = 0; _mt < 4; ++_mt) {                                        \
      _Pragma("unroll")                                                        \
      for (int _nt = 0; _nt < 4; ++_nt)                                        \
        acc[_mt][_nt] = __builtin_amdgcn_mfma_f32_16x16x32_bf16(               \
            af[_mt], bf[_nt], acc[_mt][_nt], 0, 0, 0);                         \
    }                                                                          \
    __builtin_amdgcn_s_setprio(0);                                             \
  } while (0)

  // prologue: stage tile 0 fully (8 loads); wait oldest 4 (k0 group)
  STG(0, 0, 0);
  STG(0, 1, 0);
  VM4(); SBAR(); SCHEDB();

  for (int t = 0; t < nk; ++t) {
    const int buf = t & 1, nb = buf ^ 1;
    const bool last = (t == nk - 1);

    // ---- phase 1 (kk=0): stage (t+1).k0
    LDA(buf, 0); LDB(buf, 0);
    if (!last) STG(nb, 0, t + 1);
    MMCL();
    // t.k1 (issued 2 phases ago) must be ready for phase 2
    if (last) VM0(); else VM4();
    SBAR(); SCHEDB();

    // ---- phase 2 (kk=1): stage (t+1).k1
    LDA(buf, 1); LDB(buf, 1);
    if (!last) STG(nb, 1, t + 1);
    MMCL();
    // (t+1).k0 (issued in phase 1) must be ready for next phase 1
    if (!last) { VM4(); }
    SBAR(); SCHEDB();
  }

#undef VM4
#undef VM0
#undef SBAR
#undef SCHEDB
#undef STG
#undef LDA
#undef LDB
#undef MMCL

  u16* Cbz = Cb + (size_t)blockIdx.z * sC;

  // epilogue: C/D layout col = lane&15, row = quad*4 + reg
  #pragma unroll
  for (int mt = 0; mt < 4; ++mt) {
    int grow0 = bm0 + wm + mt * 16 + quad * 4;
    #pragma unroll
    for (int nt = 0; nt < 4; ++nt) {
      int gcol = bn0 + wn + nt * 16 + l16;
      if (EPI == 3) {
        const int seg = gcol >> 10;
        const int col = gcol & 1023;
        const float* bp = (seg == 0) ? bias : (seg == 1) ? bias2 : bias3;
        u16*         cp = (seg == 0) ? Cb   : (seg == 1) ? Cb2   : Cb3;
        float bv = bp[col];
        #pragma unroll
        for (int r = 0; r < 4; ++r)
          cp[(size_t)(grow0 + r) * ldc + col] = f2b(acc[mt][nt][r] + bv);
      } else if (EPI == 4) {
        float bv = bias[gcol];
        #pragma unroll
        for (int r = 0; r < 4; ++r)
          Cbz[(size_t)(grow0 + r) * ldc + gcol] =
              f2b(gelu_exact(acc[mt][nt][r] + bv));
      } else {  // 6
        #pragma unroll
        for (int r = 0; r < 4; ++r)
          Cbz[(size_t)(grow0 + r) * ldc + gcol] = f2b(acc[mt][nt][r]);
      }
    }
  }
}

// ---- softmax over rows of 2048 ----------------------------------------------
__global__ __launch_bounds__(256) void softmax_rows(const u16* __restrict__ Sc,
                                                    u16* __restrict__ P) {
  __shared__ float sm[8];
  int row = blockIdx.x, t = threadIdx.x;
  const u16* s = Sc + (size_t)row * SEQ;
  uint4 raw = *(const uint4*)(s + t * 8);
  float v[8];
  #pragma unroll
  for (int m = 0; m < 4; ++m) {
    u32 w = ((const u32*)&raw)[m];
    v[2 * m]     = b2f((u16)(w & 0xffff)) * 0.125f;
    v[2 * m + 1] = b2f((u16)(w >> 16)) * 0.125f;
  }
  float mx = -1e30f;
  #pragma unroll
  for (int i = 0; i < 8; ++i) mx = fmaxf(mx, v[i]);
  mx = blk_max(mx, sm);
  float sum = 0.0f;
  #pragma unroll
  for (int i = 0; i < 8; ++i) { v[i] = __expf(v[i] - mx); sum += v[i]; }
  sum = blk_sum1(sum, sm);
  float inv = 1.0f / sum;
  uint4 o;
  #pragma unroll
  for (int m = 0; m < 4; ++m)
    ((u32*)&o)[m] = (u32)f2b(v[2 * m] * inv) | ((u32)f2b(v[2 * m + 1] * inv) << 16);
  *(uint4*)(P + (size_t)row * SEQ + t * 8) = o;
}

// ---- h = LN( LN(attn+x)*g_at+b_at + x )*g_ln+b_ln  -> hres bf16 -------------
__global__ __launch_bounds__(256) void ln1_fused(
    const u16* __restrict__ attn, const u16* __restrict__ xb,
    const float* __restrict__ g_at, const float* __restrict__ b_at,
    const float* __restrict__ g_ln, const float* __restrict__ b_ln,
    u16* __restrict__ hres)
{
  __shared__ float sm[8];
  int row = blockIdx.x, t = threadIdx.x;
  size_t base = (size_t)row * DIMN;
  uint2 ar = *(const uint2*)(attn + base + t * 4);
  uint2 xr4 = *(const uint2*)(xb + base + t * 4);
  float y[4], xr[4];
  float s = 0.0f, s2 = 0.0f;
  #pragma unroll
  for (int i = 0; i < 4; ++i) {
    u32 aw = ((const u32*)&ar)[i >> 1];
    u32 xw = ((const u32*)&xr4)[i >> 1];
    float av = b2f((u16)((i & 1) ? (aw >> 16) : (aw & 0xffff)));
    xr[i]    = b2f((u16)((i & 1) ? (xw >> 16) : (xw & 0xffff)));
    y[i] = av + xr[i];
    s += y[i]; s2 += y[i] * y[i];
  }
  blk_sum2(s, s2, sm);
  float m  = s * (1.0f / DIMN);
  float rs = rsqrtf(s2 * (1.0f / DIMN) - m * m + 1e-5f);
  float z[4];
  s = 0.0f; s2 = 0.0f;
  #pragma unroll
  for (int i = 0; i < 4; ++i) {
    int c = t * 4 + i;
    float at = (y[i] - m) * rs * g_at[c] + b_at[c];
    z[i] = at + xr[i];
    s += z[i]; s2 += z[i] * z[i];
  }
  blk_sum2(s, s2, sm);
  float m2  = s * (1.0f / DIMN);
  float rs2 = rsqrtf(s2 * (1.0f / DIMN) - m2 * m2 + 1e-5f);
  uint2 o;
  #pragma unroll
  for (int i = 0; i < 2; ++i) {
    int c = t * 4 + 2 * i;
    float h0 = (z[2 * i]     - m2) * rs2 * g_ln[c]     + b_ln[c];
    float h1 = (z[2 * i + 1] - m2) * rs2 * g_ln[c + 1] + b_ln[c + 1];
    ((u32*)&o)[i] = (u32)f2b(h0) | ((u32)f2b(h1) << 16);
  }
  *(uint2*)(hres + base + t * 4) = o;
}

// ---- out = LN(u + hres)*g_ln + b_ln  (bf16 in, f32 out) ---------------------
__global__ __launch_bounds__(256) void ln2_final(
    const u16* __restrict__ u, const u16* __restrict__ hres,
    const float* __restrict__ g, const float* __restrict__ bb,
    float* __restrict__ out)
{
  __shared__ float sm[8];
  int row = blockIdx.x, t = threadIdx.x;
  size_t base = (size_t)row * DIMN;
  uint2 ur = *(const uint2*)(u + base + t * 4);
  uint2 hr = *(const uint2*)(hres + base + t * 4);
  float y[4];
  float s = 0.0f, s2 = 0.0f;
  #pragma unroll
  for (int i = 0; i < 4; ++i) {
    u32 uw = ((const u32*)&ur)[i >> 1];
    u32 hw = ((const u32*)&hr)[i >> 1];
    float uv = b2f((u16)((i & 1) ? (uw >> 16) : (uw & 0xffff)));
    float hv = b2f((u16)((i & 1) ? (hw >> 16) : (hw & 0xffff)));
    y[i] = uv + hv;
    s += y[i]; s2 += y[i] * y[i];
  }
  blk_sum2(s, s2, sm);
  float m  = s * (1.0f / DIMN);
  float rs = rsqrtf(s2 * (1.0f / DIMN) - m * m + 1e-5f);
  float4 o;
  o.x = (y[0] - m) * rs * g[t * 4 + 0] + bb[t * 4 + 0];
  o.y = (y[1] - m) * rs * g[t * 4 + 1] + bb[t * 4 + 1];
  o.z = (y[2] - m) * rs * g[t * 4 + 2] + bb[t * 4 + 2];
  o.w = (y[3] - m) * rs * g[t * 4 + 3] + bb[t * 4 + 3];
  *(float4*)(out + base + t * 4) = o;
}

// ---- launch -----------------------------------------------------------------

extern "C" void kernel_launch(void* const* d_in, const int* in_sizes, int n_in,
                              void* d_out, int out_size, void* d_ws, size_t ws_size,
                              hipStream_t stream)
{
  const float* x    = (const float*)d_in[0];
  const float* Wq   = (const float*)d_in[1];
  const float* bq   = (const float*)d_in[2];
  const float* Wk   = (const float*)d_in[3];
  const float* bk   = (const float*)d_in[4];
  const float* Wv   = (const float*)d_in[5];
  const float* bv   = (const float*)d_in[6];
  const float* g_at = (const float*)d_in[7];
  const float* b_at = (const float*)d_in[8];
  const float* g_ln = (const float*)d_in[9];
  const float* b_ln = (const float*)d_in[10];
  const float* W1   = (const float*)d_in[11];
  const float* c1   = (const float*)d_in[12];
  const float* W2   = (const float*)d_in[13];
  const float* c2   = (const float*)d_in[14];
  float* out = (float*)d_out;

  // workspace layout (1 MiB units), peak 154 MiB (unchanged)
  char* ws = (char*)d_ws;
  const size_t MB = 1u << 20;
  u16* xb    = (u16*)(ws + 0 * MB);
  u16* W1T   = (u16*)(ws + 16 * MB);
  u16* W2T   = (u16*)(ws + 18 * MB);
  u16* WqkvT = (u16*)(ws + 20 * MB);
  u16* Qb    = (u16*)(ws + 26 * MB);
  u16* Kb    = (u16*)(ws + 42 * MB);
  u16* Vb    = (u16*)(ws + 58 * MB);
  u16* VT    = (u16*)(ws + 74 * MB);
  u16* Sc    = (u16*)(ws + 90 * MB);
  u16* attn  = (u16*)(ws + 90 * MB);
  u16* hres  = (u16*)(ws + 106 * MB);
  u16* Pb    = (u16*)(ws + 122 * MB);
  u16* tb    = Kb;   // FFN mid, K dead
  u16* ub    = Vb;   // FFN out, Vb dead

  // prep
  conv_x<<<(TOKS * DIMN) / 1024, 256, 0, stream>>>(x, xb);
  transpose_w5<<<dim3(32, 32, 5), dim3(32, 8), 0, stream>>>(
      Wq, Wk, Wv, W1, W2, WqkvT, W1T, W2T);

  // fused QKV projection: [8192,1024] @ [3072,1024]^T
  // grid 64x24 = 1536 blocks = 3 exact rounds of 512 co-resident
  gemm128p<3, 1><<<dim3(64, 24), 256, 0, stream>>>(
      xb, WqkvT, Qb, Kb, Vb, bq, bk, bv,
      TOKS, 3 * DIMN, DIMN, DIMN, 0, 0, 0);

  // V -> V^T per batch
  transpose_v<<<dim3(32, 64, NBAT), dim3(32, 8), 0, stream>>>(Vb, VT);

  // scores: 16x16x4 = 1024 blocks = 2 exact rounds
  gemm128p<6, 0><<<dim3(16, 16, NBAT), 256, 0, stream>>>(
      Qb, Kb, Sc, nullptr, nullptr, nullptr, nullptr, nullptr,
      SEQ, SEQ, DIMN, SEQ,
      (size_t)SEQ * DIMN, (size_t)SEQ * DIMN, (size_t)SEQ * SEQ);
  softmax_rows<<<TOKS, 256, 0, stream>>>(Sc, Pb);

  // PV: 16x8x4 = 512 blocks = 1 exact round
  gemm128p<6, 0><<<dim3(16, 8, NBAT), 256, 0, stream>>>(
      Pb, VT, attn, nullptr, nullptr, nullptr, nullptr, nullptr,
      SEQ, DIMN, SEQ, DIMN,
      (size_t)SEQ * SEQ, (size_t)DIMN * SEQ, (size_t)SEQ * DIMN);

  // h = LN(LN(attn+x)+x) -> hres bf16
  ln1_fused<<<TOKS, 256, 0, stream>>>(attn, xb, g_at, b_at, g_ln, b_ln, hres);

  // FFN: 64x8 = 512 blocks = 1 exact round each
  gemm128p<4, 1><<<dim3(64, 8), 256, 0, stream>>>(
      hres, W1T, tb, nullptr, nullptr, c1, nullptr, nullptr,
      TOKS, DIMN, DIMN, DIMN, 0, 0, 0);
  gemm128p<4, 1><<<dim3(64, 8), 256, 0, stream>>>(
      tb, W2T, ub, nullptr, nullptr, c2, nullptr, nullptr,
      TOKS, DIMN, DIMN, DIMN, 0, 0, 0);

  // out = LN(u + h)
  ln2_final<<<TOKS, 256, 0, stream>>>(ub, hres, g_ln, b_ln, out);
}

// Round 4
// 362.609 us; speedup vs baseline: 1.0846x; 1.0220x over previous
//
#include <hip/hip_runtime.h>
#include <cstdint>
#include <cstddef>

// Problem constants
#define DIMN 1024
#define SEQ  2048
#define NBAT 4
#define TOKS (NBAT * SEQ)   // 8192

typedef unsigned short u16;
typedef unsigned int   u32;

typedef __bf16 bf16x8 __attribute__((ext_vector_type(8)));
typedef float  f32x4  __attribute__((ext_vector_type(4)));

#define AS1 __attribute__((address_space(1)))
#define AS3 __attribute__((address_space(3)))

// ---- helpers ----------------------------------------------------------------

__device__ __forceinline__ u16 f2b(float f) {
  union { float f; u32 u; } v; v.f = f;
  u32 r = v.u + 0x7fffu + ((v.u >> 16) & 1u);   // round-to-nearest-even
  return (u16)(r >> 16);
}

__device__ __forceinline__ float b2f(u16 b) {
  union { u32 u; float f; } v; v.u = ((u32)b) << 16;
  return v.f;
}

__device__ __forceinline__ float gelu_exact(float v) {
  return 0.5f * v * (1.0f + erff(v * 0.70710678118654752f));
}

__device__ __forceinline__ void blk_sum2(float& a, float& b, float* sm) {
  #pragma unroll
  for (int o = 32; o >= 1; o >>= 1) {
    a += __shfl_xor(a, o, 64);
    b += __shfl_xor(b, o, 64);
  }
  int w = threadIdx.x >> 6;
  if ((threadIdx.x & 63) == 0) { sm[w] = a; sm[4 + w] = b; }
  __syncthreads();
  a = sm[0] + sm[1] + sm[2] + sm[3];
  b = sm[4] + sm[5] + sm[6] + sm[7];
  __syncthreads();
}

__device__ __forceinline__ float blk_max(float a, float* sm) {
  #pragma unroll
  for (int o = 32; o >= 1; o >>= 1) a = fmaxf(a, __shfl_xor(a, o, 64));
  int w = threadIdx.x >> 6;
  if ((threadIdx.x & 63) == 0) sm[w] = a;
  __syncthreads();
  float r = fmaxf(fmaxf(sm[0], sm[1]), fmaxf(sm[2], sm[3]));
  __syncthreads();
  return r;
}

__device__ __forceinline__ float blk_sum1(float a, float* sm) {
  #pragma unroll
  for (int o = 32; o >= 1; o >>= 1) a += __shfl_xor(a, o, 64);
  int w = threadIdx.x >> 6;
  if ((threadIdx.x & 63) == 0) sm[w] = a;
  __syncthreads();
  float r = sm[0] + sm[1] + sm[2] + sm[3];
  __syncthreads();
  return r;
}

// ---- prep kernels -----------------------------------------------------------

__global__ __launch_bounds__(256) void conv_x(const float* __restrict__ x,
                                              u16* __restrict__ xb) {
  size_t i = ((size_t)blockIdx.x * 256 + threadIdx.x) * 4;
  float4 v = *(const float4*)(x + i);
  uint2 o;
  o.x = (u32)f2b(v.x) | ((u32)f2b(v.y) << 16);
  o.y = (u32)f2b(v.z) | ((u32)f2b(v.w) << 16);
  *(uint2*)(xb + i) = o;
}

// All 5 weight transposes in one dispatch: W [K][N] f32 -> WT [N][K] bf16.
__global__ __launch_bounds__(256) void transpose_w5(
    const float* __restrict__ Wq, const float* __restrict__ Wk,
    const float* __restrict__ Wv, const float* __restrict__ W1,
    const float* __restrict__ W2,
    u16* __restrict__ Wqkv, u16* __restrict__ W1T, u16* __restrict__ W2T)
{
  const float* W; u16* T;
  switch (blockIdx.z) {
    case 0: W = Wq; T = Wqkv;                      break;
    case 1: W = Wk; T = Wqkv + 1 * DIMN * DIMN;    break;
    case 2: W = Wv; T = Wqkv + 2 * DIMN * DIMN;    break;
    case 3: W = W1; T = W1T;                       break;
    default: W = W2; T = W2T;                      break;
  }
  __shared__ float t[32][33];
  int tx = threadIdx.x, ty = threadIdx.y;
  int k0 = blockIdx.x * 32, n0 = blockIdx.y * 32;
  #pragma unroll
  for (int j = 0; j < 32; j += 8)
    t[ty + j][tx] = W[(size_t)(k0 + ty + j) * DIMN + n0 + tx];
  __syncthreads();
  #pragma unroll
  for (int j = 0; j < 32; j += 8)
    T[(size_t)(n0 + ty + j) * DIMN + k0 + tx] = f2b(t[tx][ty + j]);
}

// Vb[b][tok][d] bf16 -> VT[b][d][tok] bf16
__global__ __launch_bounds__(256) void transpose_v(const u16* __restrict__ Vb,
                                                   u16* __restrict__ VT) {
  __shared__ u16 t[32][33];
  int tx = threadIdx.x, ty = threadIdx.y;
  int d0 = blockIdx.x * 32, t0 = blockIdx.y * 32;
  const u16* src = Vb + (size_t)blockIdx.z * SEQ * DIMN;
  u16*       dst = VT + (size_t)blockIdx.z * DIMN * SEQ;
  #pragma unroll
  for (int j = 0; j < 32; j += 8)
    t[ty + j][tx] = src[(size_t)(t0 + ty + j) * DIMN + d0 + tx];
  __syncthreads();
  #pragma unroll
  for (int j = 0; j < 32; j += 8)
    dst[(size_t)(d0 + ty + j) * SEQ + t0 + tx] = t[tx][ty + j];
}

// ---- 128x128 MFMA GEMM, counted-vmcnt K-pipeline, 2 blocks/CU ---------------
// (See round-3 notes.) A/B this round: sched_barrier(0) pins REMOVED (m141:
// order-pinning defeats the compiler scheduler). The asm "memory" clobber on
// the counted vmcnt still fences ds_read/global_load_lds motion.
template <int EPI, int SWZ>
__global__ __launch_bounds__(256, 2) void gemm128p(
    const u16* __restrict__ A, const u16* __restrict__ Bm,
    u16* __restrict__ Cb, u16* __restrict__ Cb2, u16* __restrict__ Cb3,
    const float* __restrict__ bias, const float* __restrict__ bias2,
    const float* __restrict__ bias3,
    int M, int N, int K, int ldc,
    size_t sA, size_t sB, size_t sC)
{
  __shared__ u16 AB[2][2][2][128 * 32];   // [buf][A/B][khalf][row*32+col]

  const int tid = threadIdx.x;

  int bm0, bn0;
  if (SWZ == 1) {
    const int id   = blockIdx.y * gridDim.x + blockIdx.x;
    const int xcd  = id & 7;
    const int idx  = id >> 3;
    const int band = gridDim.x >> 3;          // bm tiles per XCD
    const int bm_l = idx % band;
    const int bn   = idx / band;
    bm0 = (xcd * band + bm_l) * 128;
    bn0 = bn * 128;
  } else {
    bm0 = blockIdx.x * 128;
    bn0 = blockIdx.y * 128;
  }

  A  += (size_t)blockIdx.z * sA;
  Bm += (size_t)blockIdx.z * sB;

  const int wave = tid >> 6, lane = tid & 63;
  const int wm   = (wave >> 1) * 64, wn = (wave & 1) * 64;
  const int l16  = lane & 15, quad = lane >> 4;
  const int rs8  = (quad ^ ((l16 >> 1) & 3)) << 3;
  const int cg8  = ((lane & 3) ^ ((lane >> 3) & 3)) << 3;
  const int srow = wave * 32 + (lane >> 2);

  f32x4 acc[4][4] = {};
  bf16x8 af[4], bf[4];

  const int nk = K >> 6;

#define VM4() asm volatile("s_waitcnt vmcnt(4)" ::: "memory")
#define VM0() asm volatile("s_waitcnt vmcnt(0)" ::: "memory")
#define SBAR() __builtin_amdgcn_s_barrier()

#define STG(BUF, KH, KT) do {                                                  \
    const int _kc = (KT) * 64 + (KH) * 32;                                     \
    _Pragma("unroll")                                                          \
    for (int _j = 0; _j < 2; ++_j) {                                           \
      const u16* _gA = A  + (size_t)(bm0 + srow + _j * 16) * K + _kc + cg8;    \
      const u16* _gB = Bm + (size_t)(bn0 + srow + _j * 16) * K + _kc + cg8;    \
      u16* _lA = &AB[BUF][0][KH][(wave * 128 + _j * 64) * 8];                  \
      u16* _lB = &AB[BUF][1][KH][(wave * 128 + _j * 64) * 8];                  \
      __builtin_amdgcn_global_load_lds((const AS1 void*)_gA, (AS3 void*)_lA,   \
                                       16, 0, 0);                              \
      __builtin_amdgcn_global_load_lds((const AS1 void*)_gB, (AS3 void*)_lB,   \
                                       16, 0, 0);                              \
    }                                                                          \
  } while (0)

#define LDA(BUF, KH) do {                                                      \
    const u16* _u = &AB[BUF][0][KH][0];                                        \
    _Pragma("unroll")                                                          \
    for (int _i = 0; _i < 4; ++_i)                                             \
      af[_i] = *(const bf16x8*)(_u + (wm + _i * 16 + l16) * 32 + rs8);         \
  } while (0)

#define LDB(BUF, KH) do {                                                      \
    const u16* _u = &AB[BUF][1][KH][0];                                        \
    _Pragma("unroll")                                                          \
    for (int _i = 0; _i < 4; ++_i)                                             \
      bf[_i] = *(const bf16x8*)(_u + (wn + _i * 16 + l16) * 32 + rs8);         \
  } while (0)

#define MMCL() do {                                                            \
    __builtin_amdgcn_s_setprio(1);                                             \
    _Pragma("unroll")                                                          \
    for (int _mt = 0; _mt < 4; ++_mt) {                                        \
      _Pragma("unroll")                                                        \
      for (int _nt = 0; _nt < 4; ++_nt)                                        \
        acc[_mt][_nt] = __builtin_amdgcn_mfma_f32_16x16x32_bf16(               \
            af[_mt], bf[_nt], acc[_mt][_nt], 0, 0, 0);                         \
    }                                                                          \
    __builtin_amdgcn_s_setprio(0);                                             \
  } while (0)

  // prologue: stage tile 0 fully (8 loads); wait oldest 4 (k0 group)
  STG(0, 0, 0);
  STG(0, 1, 0);
  VM4(); SBAR();

  for (int t = 0; t < nk; ++t) {
    const int buf = t & 1, nb = buf ^ 1;
    const bool last = (t == nk - 1);

    // ---- phase 1 (kk=0): stage (t+1).k0
    LDA(buf, 0); LDB(buf, 0);
    if (!last) STG(nb, 0, t + 1);
    MMCL();
    if (last) VM0(); else VM4();
    SBAR();

    // ---- phase 2 (kk=1): stage (t+1).k1
    LDA(buf, 1); LDB(buf, 1);
    if (!last) STG(nb, 1, t + 1);
    MMCL();
    if (!last) { VM4(); }
    SBAR();
  }

#undef VM4
#undef VM0
#undef SBAR
#undef STG
#undef LDA
#undef LDB
#undef MMCL

  u16* Cbz = Cb + (size_t)blockIdx.z * sC;

  #pragma unroll
  for (int mt = 0; mt < 4; ++mt) {
    int grow0 = bm0 + wm + mt * 16 + quad * 4;
    #pragma unroll
    for (int nt = 0; nt < 4; ++nt) {
      int gcol = bn0 + wn + nt * 16 + l16;
      if (EPI == 3) {
        const int seg = gcol >> 10;
        const int col = gcol & 1023;
        const float* bp = (seg == 0) ? bias : (seg == 1) ? bias2 : bias3;
        u16*         cp = (seg == 0) ? Cb   : (seg == 1) ? Cb2   : Cb3;
        float bv = bp[col];
        #pragma unroll
        for (int r = 0; r < 4; ++r)
          cp[(size_t)(grow0 + r) * ldc + col] = f2b(acc[mt][nt][r] + bv);
      } else if (EPI == 4) {
        float bv = bias[gcol];
        #pragma unroll
        for (int r = 0; r < 4; ++r)
          Cbz[(size_t)(grow0 + r) * ldc + gcol] =
              f2b(gelu_exact(acc[mt][nt][r] + bv));
      } else {  // 6
        #pragma unroll
        for (int r = 0; r < 4; ++r)
          Cbz[(size_t)(grow0 + r) * ldc + gcol] = f2b(acc[mt][nt][r]);
      }
    }
  }
}

// ---- 256x256 MFMA GEMM, m201-style 8-phase K-pipeline -----------------------
// Round-2 body; A/B this round: all sched_barrier(0) pins REMOVED.
// 512 threads = 8 waves (2M x 4N), wave tile 128x64, acc[8][4].
// LDS AB[buf][A/B][khalf][256x32] bf16 = 128 KiB, 1 block/CU.
// Counted vmcnt(8) at even-phase ends; stages land 6 phases before first read.
template <int EPI, int SWZ>
__global__ __launch_bounds__(512, 2) void gemm256(
    const u16* __restrict__ A, const u16* __restrict__ Bm,
    u16* __restrict__ Cb, u16* __restrict__ Cb2, u16* __restrict__ Cb3,
    const float* __restrict__ bias, const float* __restrict__ bias2,
    const float* __restrict__ bias3,
    int M, int N, int K, int ldc,
    size_t sA, size_t sB, size_t sC)
{
  __shared__ u16 AB[2][2][2][256 * 32];   // [buf][A/B][khalf][row*32+col]

  const int tid = threadIdx.x;

  int bm0, bn0;
  if (SWZ == 1) {
    const int id   = blockIdx.y * gridDim.x + blockIdx.x;
    const int xcd  = id & 7;
    const int idx  = id >> 3;
    const int band = gridDim.x >> 3;
    const int bm_l = idx % band;
    const int bn   = idx / band;
    bm0 = (xcd * band + bm_l) * 256;
    bn0 = bn * 256;
  } else {
    bm0 = blockIdx.x * 256;
    bn0 = blockIdx.y * 256;
  }

  A  += (size_t)blockIdx.z * sA;
  Bm += (size_t)blockIdx.z * sB;

  const int wave = tid >> 6, lane = tid & 63;
  const int wm   = (wave >> 2) * 128, wn = (wave & 3) * 64;
  const int l16  = lane & 15, quad = lane >> 4;
  const int rs8  = (quad ^ ((l16 >> 1) & 3)) << 3;
  const int cg8  = ((lane & 3) ^ ((lane >> 3) & 3)) << 3;
  const int srow = wave * 32 + (lane >> 2);

  f32x4 acc[8][4] = {};
  bf16x8 af[4], bf[4];

  const int nk  = K >> 6;
  const int nit = nk >> 1;

#define VM8() asm volatile("s_waitcnt vmcnt(8)" ::: "memory")
#define VM4() asm volatile("s_waitcnt vmcnt(4)" ::: "memory")
#define VM0() asm volatile("s_waitcnt vmcnt(0)" ::: "memory")
#define SBAR() __builtin_amdgcn_s_barrier()

#define STG(BUF, ABI, KH, KT) do {                                             \
    const u16* _P   = (ABI) ? Bm : A;                                          \
    const int _b0   = (ABI) ? bn0 : bm0;                                       \
    const int _kc   = (KT) * 64 + (KH) * 32;                                   \
    _Pragma("unroll")                                                          \
    for (int _j = 0; _j < 2; ++_j) {                                           \
      const u16* _g = _P + (size_t)(_b0 + srow + _j * 16) * K + _kc + cg8;     \
      u16* _l = &AB[BUF][ABI][KH][(wave * 128 + _j * 64) * 8];                 \
      __builtin_amdgcn_global_load_lds((const AS1 void*)_g, (AS3 void*)_l,     \
                                       16, 0, 0);                              \
    }                                                                          \
  } while (0)

#define LDA(BUF, KH, MH) do {                                                  \
    const u16* _u = &AB[BUF][0][KH][0];                                        \
    _Pragma("unroll")                                                          \
    for (int _i = 0; _i < 4; ++_i)                                             \
      af[_i] = *(const bf16x8*)(_u + (wm + (MH) * 64 + _i * 16 + l16) * 32     \
                                  + rs8);                                      \
  } while (0)

#define LDB(BUF, KH) do {                                                      \
    const u16* _u = &AB[BUF][1][KH][0];                                        \
    _Pragma("unroll")                                                          \
    for (int _i = 0; _i < 4; ++_i)                                             \
      bf[_i] = *(const bf16x8*)(_u + (wn + _i * 16 + l16) * 32 + rs8);         \
  } while (0)

#define MMCL(MH) do {                                                          \
    __builtin_amdgcn_s_setprio(1);                                             \
    _Pragma("unroll")                                                          \
    for (int _mt = 0; _mt < 4; ++_mt) {                                        \
      _Pragma("unroll")                                                        \
      for (int _nt = 0; _nt < 4; ++_nt)                                        \
        acc[(MH) * 4 + _mt][_nt] = __builtin_amdgcn_mfma_f32_16x16x32_bf16(    \
            af[_mt], bf[_nt], acc[(MH) * 4 + _mt][_nt], 0, 0, 0);              \
    }                                                                          \
    __builtin_amdgcn_s_setprio(0);                                             \
  } while (0)

  // prologue: t0 full (4 units) + t1.k0 (2 units); wait oldest 2 units
  STG(0, 0, 0, 0); STG(0, 1, 0, 0);
  STG(0, 0, 1, 0); STG(0, 1, 1, 0);
  STG(1, 0, 0, 1); STG(1, 1, 0, 1);
  VM8(); SBAR();

  for (int i = 0; i < nit; ++i) {
    const int t1 = 2 * i + 1;
    const bool last = (i == nit - 1);

    // P1: buf0 kk0 mh0 | stage t1.A.k1
    LDA(0, 0, 0); LDB(0, 0);
    STG(1, 0, 1, t1);
    SBAR();
    MMCL(0);
    SBAR();

    // P2: buf0 kk0 mh1 | stage t1.B.k1 | wait: t0.k1 ready for P3
    LDA(0, 0, 1);
    STG(1, 1, 1, t1);
    SBAR();
    MMCL(1);
    VM8(); SBAR();

    // P3: buf0 kk1 mh0 | stage t2.A.k0
    LDA(0, 1, 0); LDB(0, 1);
    if (!last) STG(0, 0, 0, t1 + 1);
    SBAR();
    MMCL(0);
    SBAR();

    // P4: buf0 kk1 mh1 | stage t2.B.k0 | wait: t1.k0 ready for P5
    LDA(0, 1, 1);
    if (!last) STG(0, 1, 0, t1 + 1);
    SBAR();
    MMCL(1);
    if (last) VM4(); else VM8();
    SBAR();

    // P5: buf1 kk0 mh0 | stage t2.A.k1
    LDA(1, 0, 0); LDB(1, 0);
    if (!last) STG(0, 0, 1, t1 + 1);
    SBAR();
    MMCL(0);
    SBAR();

    // P6: buf1 kk0 mh1 | stage t2.B.k1 | wait: t1.k1 ready for P7
    LDA(1, 0, 1);
    if (!last) STG(0, 1, 1, t1 + 1);
    SBAR();
    MMCL(1);
    if (last) VM0(); else VM8();
    SBAR();

    // P7: buf1 kk1 mh0 | stage t3.A.k0
    LDA(1, 1, 0); LDB(1, 1);
    if (!last) STG(1, 0, 0, t1 + 2);
    SBAR();
    MMCL(0);
    SBAR();

    // P8: buf1 kk1 mh1 | stage t3.B.k0 | wait: t2.k0 ready for next P1
    LDA(1, 1, 1);
    if (!last) STG(1, 1, 0, t1 + 2);
    SBAR();
    MMCL(1);
    if (!last) { VM8(); }
    SBAR();
  }

#undef VM8
#undef VM4
#undef VM0
#undef SBAR
#undef STG
#undef LDA
#undef LDB
#undef MMCL

  u16* Cbz = Cb + (size_t)blockIdx.z * sC;

  #pragma unroll
  for (int mt = 0; mt < 8; ++mt) {
    int grow0 = bm0 + wm + mt * 16 + quad * 4;
    #pragma unroll
    for (int nt = 0; nt < 4; ++nt) {
      int gcol = bn0 + wn + nt * 16 + l16;
      if (EPI == 3) {
        const int seg = gcol >> 10;
        const int col = gcol & 1023;
        const float* bp = (seg == 0) ? bias : (seg == 1) ? bias2 : bias3;
        u16*         cp = (seg == 0) ? Cb   : (seg == 1) ? Cb2   : Cb3;
        float bv = bp[col];
        #pragma unroll
        for (int r = 0; r < 4; ++r)
          cp[(size_t)(grow0 + r) * ldc + col] = f2b(acc[mt][nt][r] + bv);
      } else if (EPI == 4) {
        float bv = bias[gcol];
        #pragma unroll
        for (int r = 0; r < 4; ++r)
          Cbz[(size_t)(grow0 + r) * ldc + gcol] =
              f2b(gelu_exact(acc[mt][nt][r] + bv));
      } else {  // 6
        #pragma unroll
        for (int r = 0; r < 4; ++r)
          Cbz[(size_t)(grow0 + r) * ldc + gcol] = f2b(acc[mt][nt][r]);
      }
    }
  }
}

// ---- softmax over rows of 2048 ----------------------------------------------
__global__ __launch_bounds__(256) void softmax_rows(const u16* __restrict__ Sc,
                                                    u16* __restrict__ P) {
  __shared__ float sm[8];
  int row = blockIdx.x, t = threadIdx.x;
  const u16* s = Sc + (size_t)row * SEQ;
  uint4 raw = *(const uint4*)(s + t * 8);
  float v[8];
  #pragma unroll
  for (int m = 0; m < 4; ++m) {
    u32 w = ((const u32*)&raw)[m];
    v[2 * m]     = b2f((u16)(w & 0xffff)) * 0.125f;
    v[2 * m + 1] = b2f((u16)(w >> 16)) * 0.125f;
  }
  float mx = -1e30f;
  #pragma unroll
  for (int i = 0; i < 8; ++i) mx = fmaxf(mx, v[i]);
  mx = blk_max(mx, sm);
  float sum = 0.0f;
  #pragma unroll
  for (int i = 0; i < 8; ++i) { v[i] = __expf(v[i] - mx); sum += v[i]; }
  sum = blk_sum1(sum, sm);
  float inv = 1.0f / sum;
  uint4 o;
  #pragma unroll
  for (int m = 0; m < 4; ++m)
    ((u32*)&o)[m] = (u32)f2b(v[2 * m] * inv) | ((u32)f2b(v[2 * m + 1] * inv) << 16);
  *(uint4*)(P + (size_t)row * SEQ + t * 8) = o;
}

// ---- h = LN( LN(attn+x)*g_at+b_at + x )*g_ln+b_ln  -> hres bf16 -------------
__global__ __launch_bounds__(256) void ln1_fused(
    const u16* __restrict__ attn, const u16* __restrict__ xb,
    const float* __restrict__ g_at, const float* __restrict__ b_at,
    const float* __restrict__ g_ln, const float* __restrict__ b_ln,
    u16* __restrict__ hres)
{
  __shared__ float sm[8];
  int row = blockIdx.x, t = threadIdx.x;
  size_t base = (size_t)row * DIMN;
  uint2 ar = *(const uint2*)(attn + base + t * 4);
  uint2 xr4 = *(const uint2*)(xb + base + t * 4);
  float y[4], xr[4];
  float s = 0.0f, s2 = 0.0f;
  #pragma unroll
  for (int i = 0; i < 4; ++i) {
    u32 aw = ((const u32*)&ar)[i >> 1];
    u32 xw = ((const u32*)&xr4)[i >> 1];
    float av = b2f((u16)((i & 1) ? (aw >> 16) : (aw & 0xffff)));
    xr[i]    = b2f((u16)((i & 1) ? (xw >> 16) : (xw & 0xffff)));
    y[i] = av + xr[i];
    s += y[i]; s2 += y[i] * y[i];
  }
  blk_sum2(s, s2, sm);
  float m  = s * (1.0f / DIMN);
  float rs = rsqrtf(s2 * (1.0f / DIMN) - m * m + 1e-5f);
  float z[4];
  s = 0.0f; s2 = 0.0f;
  #pragma unroll
  for (int i = 0; i < 4; ++i) {
    int c = t * 4 + i;
    float at = (y[i] - m) * rs * g_at[c] + b_at[c];
    z[i] = at + xr[i];
    s += z[i]; s2 += z[i] * z[i];
  }
  blk_sum2(s, s2, sm);
  float m2  = s * (1.0f / DIMN);
  float rs2 = rsqrtf(s2 * (1.0f / DIMN) - m2 * m2 + 1e-5f);
  uint2 o;
  #pragma unroll
  for (int i = 0; i < 2; ++i) {
    int c = t * 4 + 2 * i;
    float h0 = (z[2 * i]     - m2) * rs2 * g_ln[c]     + b_ln[c];
    float h1 = (z[2 * i + 1] - m2) * rs2 * g_ln[c + 1] + b_ln[c + 1];
    ((u32*)&o)[i] = (u32)f2b(h0) | ((u32)f2b(h1) << 16);
  }
  *(uint2*)(hres + base + t * 4) = o;
}

// ---- out = LN(u + hres)*g_ln + b_ln  (bf16 in, f32 out) ---------------------
__global__ __launch_bounds__(256) void ln2_final(
    const u16* __restrict__ u, const u16* __restrict__ hres,
    const float* __restrict__ g, const float* __restrict__ bb,
    float* __restrict__ out)
{
  __shared__ float sm[8];
  int row = blockIdx.x, t = threadIdx.x;
  size_t base = (size_t)row * DIMN;
  uint2 ur = *(const uint2*)(u + base + t * 4);
  uint2 hr = *(const uint2*)(hres + base + t * 4);
  float y[4];
  float s = 0.0f, s2 = 0.0f;
  #pragma unroll
  for (int i = 0; i < 4; ++i) {
    u32 uw = ((const u32*)&ur)[i >> 1];
    u32 hw = ((const u32*)&hr)[i >> 1];
    float uv = b2f((u16)((i & 1) ? (uw >> 16) : (uw & 0xffff)));
    float hv = b2f((u16)((i & 1) ? (hw >> 16) : (hw & 0xffff)));
    y[i] = uv + hv;
    s += y[i]; s2 += y[i] * y[i];
  }
  blk_sum2(s, s2, sm);
  float m  = s * (1.0f / DIMN);
  float rs = rsqrtf(s2 * (1.0f / DIMN) - m * m + 1e-5f);
  float4 o;
  o.x = (y[0] - m) * rs * g[t * 4 + 0] + bb[t * 4 + 0];
  o.y = (y[1] - m) * rs * g[t * 4 + 1] + bb[t * 4 + 1];
  o.z = (y[2] - m) * rs * g[t * 4 + 2] + bb[t * 4 + 2];
  o.w = (y[3] - m) * rs * g[t * 4 + 3] + bb[t * 4 + 3];
  *(float4*)(out + base + t * 4) = o;
}

// ---- launch -----------------------------------------------------------------

extern "C" void kernel_launch(void* const* d_in, const int* in_sizes, int n_in,
                              void* d_out, int out_size, void* d_ws, size_t ws_size,
                              hipStream_t stream)
{
  const float* x    = (const float*)d_in[0];
  const float* Wq   = (const float*)d_in[1];
  const float* bq   = (const float*)d_in[2];
  const float* Wk   = (const float*)d_in[3];
  const float* bk   = (const float*)d_in[4];
  const float* Wv   = (const float*)d_in[5];
  const float* bv   = (const float*)d_in[6];
  const float* g_at = (const float*)d_in[7];
  const float* b_at = (const float*)d_in[8];
  const float* g_ln = (const float*)d_in[9];
  const float* b_ln = (const float*)d_in[10];
  const float* W1   = (const float*)d_in[11];
  const float* c1   = (const float*)d_in[12];
  const float* W2   = (const float*)d_in[13];
  const float* c2   = (const float*)d_in[14];
  float* out = (float*)d_out;

  // workspace layout (1 MiB units), peak 154 MiB (unchanged)
  char* ws = (char*)d_ws;
  const size_t MB = 1u << 20;
  u16* xb    = (u16*)(ws + 0 * MB);
  u16* W1T   = (u16*)(ws + 16 * MB);
  u16* W2T   = (u16*)(ws + 18 * MB);
  u16* WqkvT = (u16*)(ws + 20 * MB);
  u16* Qb    = (u16*)(ws + 26 * MB);
  u16* Kb    = (u16*)(ws + 42 * MB);
  u16* Vb    = (u16*)(ws + 58 * MB);
  u16* VT    = (u16*)(ws + 74 * MB);
  u16* Sc    = (u16*)(ws + 90 * MB);
  u16* attn  = (u16*)(ws + 90 * MB);
  u16* hres  = (u16*)(ws + 106 * MB);
  u16* Pb    = (u16*)(ws + 122 * MB);
  u16* tb    = Kb;   // FFN mid, K dead
  u16* ub    = Vb;   // FFN out, Vb dead

  // prep
  conv_x<<<(TOKS * DIMN) / 1024, 256, 0, stream>>>(x, xb);
  transpose_w5<<<dim3(32, 32, 5), dim3(32, 8), 0, stream>>>(
      Wq, Wk, Wv, W1, W2, WqkvT, W1T, W2T);

  // fused QKV projection: [8192,1024] @ [3072,1024]^T on the 8-phase 256^2
  gemm256<3, 1><<<dim3(32, 12), 512, 0, stream>>>(
      xb, WqkvT, Qb, Kb, Vb, bq, bk, bv,
      TOKS, 3 * DIMN, DIMN, DIMN, 0, 0, 0);

  // V -> V^T per batch
  transpose_v<<<dim3(32, 64, NBAT), dim3(32, 8), 0, stream>>>(Vb, VT);

  // scores: 8x8x4 = 256 blocks = exactly 1 round on the 8-phase 256^2
  gemm256<6, 0><<<dim3(8, 8, NBAT), 512, 0, stream>>>(
      Qb, Kb, Sc, nullptr, nullptr, nullptr, nullptr, nullptr,
      SEQ, SEQ, DIMN, SEQ,
      (size_t)SEQ * DIMN, (size_t)SEQ * DIMN, (size_t)SEQ * SEQ);
  softmax_rows<<<TOKS, 256, 0, stream>>>(Sc, Pb);

  // PV: 16x8x4 = 512 blocks = 1 exact round at 2 blk/CU
  gemm128p<6, 0><<<dim3(16, 8, NBAT), 256, 0, stream>>>(
      Pb, VT, attn, nullptr, nullptr, nullptr, nullptr, nullptr,
      SEQ, DIMN, SEQ, DIMN,
      (size_t)SEQ * SEQ, (size_t)DIMN * SEQ, (size_t)SEQ * DIMN);

  // h = LN(LN(attn+x)+x) -> hres bf16
  ln1_fused<<<TOKS, 256, 0, stream>>>(attn, xb, g_at, b_at, g_ln, b_ln, hres);

  // FFN: 64x8 = 512 blocks = 1 exact round each
  gemm128p<4, 1><<<dim3(64, 8), 256, 0, stream>>>(
      hres, W1T, tb, nullptr, nullptr, c1, nullptr, nullptr,
      TOKS, DIMN, DIMN, DIMN, 0, 0, 0);
  gemm128p<4, 1><<<dim3(64, 8), 256, 0, stream>>>(
      tb, W2T, ub, nullptr, nullptr, c2, nullptr, nullptr,
      TOKS, DIMN, DIMN, DIMN, 0, 0, 0);

  // out = LN(u + h)
  ln2_final<<<TOKS, 256, 0, stream>>>(ub, hres, g_ln, b_ln, out);
}